// Round 1
// baseline (8498.834 us; speedup 1.0000x reference)
//
#include <hip/hip_runtime.h>
#include <hip/hip_bf16.h>
#include <math.h>

#define B_  32
#define L_  256
#define PD_ 164
#define D_  240
#define H_  16
#define NB_ 6
#define NC_ 250
#define DK_ 15
#define HID_ 480
#define LP_ 257            // L+1
#define SCALE_ 0.2581988897471611f   // 1/sqrt(15)

// ---------------- mask ----------------
__global__ void mask_kernel(const float* __restrict__ x, float* __restrict__ mask) {
    int idx = blockIdx.x * blockDim.x + threadIdx.x;
    if (idx >= B_ * LP_) return;
    int b = idx / LP_, l = idx % LP_;
    if (l == 0) { mask[idx] = 0.f; return; }
    const float* xr = x + ((size_t)b * L_ + (l - 1)) * PD_;
    float mx = -1e30f;
    for (int j = 0; j < PD_; j++) mx = fmaxf(mx, xr[j]);
    mask[idx] = (mx == 0.f) ? 1.f : 0.f;
}

// ---------------- generic GEMM: C = A[M,K] @ B[K,N] (+bias) (relu) (accum) ----
// flags: 1 = relu, 2 = accumulate into C (residual)
__global__ void gemm_kernel(const float* __restrict__ A, const float* __restrict__ Bm,
                            const float* __restrict__ bias, float* __restrict__ C,
                            int M, int N, int K, int flags) {
    int idx = blockIdx.x * blockDim.x + threadIdx.x;
    if (idx >= M * N) return;
    int m = idx / N, n = idx - m * N;
    const float* a = A + (size_t)m * K;
    const float* b = Bm + n;
    float s0 = 0.f, s1 = 0.f, s2 = 0.f, s3 = 0.f;
    int kk = 0;
    for (; kk + 4 <= K; kk += 4) {
        s0 += a[kk]     * b[(size_t)kk * N];
        s1 += a[kk + 1] * b[(size_t)(kk + 1) * N];
        s2 += a[kk + 2] * b[(size_t)(kk + 2) * N];
        s3 += a[kk + 3] * b[(size_t)(kk + 3) * N];
    }
    float s = (s0 + s1) + (s2 + s3);
    for (; kk < K; kk++) s += a[kk] * b[(size_t)kk * N];
    if (bias) s += bias[n];
    if (flags & 1) s = fmaxf(s, 0.f);
    if (flags & 2) C[idx] += s; else C[idx] = s;
}

// ---------------- row LayerNorm (row length n <= 512, block 256) -------------
__global__ void ln_kernel(const float* __restrict__ in, float* __restrict__ out,
                          const float* __restrict__ g, const float* __restrict__ bb,
                          int n, int relu) {
    int row = blockIdx.x;
    const float* x = in + (size_t)row * n;
    float* y = out + (size_t)row * n;
    int t = threadIdx.x;
    float v0 = (t < n) ? x[t] : 0.f;
    float v1 = (t + 256 < n) ? x[t + 256] : 0.f;
    __shared__ float red[256];
    red[t] = v0 + v1;
    __syncthreads();
    for (int off = 128; off > 0; off >>= 1) {
        if (t < off) red[t] += red[t + off];
        __syncthreads();
    }
    float mean = red[0] / n;
    __syncthreads();
    float d0 = (t < n) ? v0 - mean : 0.f;
    float d1 = (t + 256 < n) ? v1 - mean : 0.f;
    red[t] = d0 * d0 + d1 * d1;
    __syncthreads();
    for (int off = 128; off > 0; off >>= 1) {
        if (t < off) red[t] += red[t + off];
        __syncthreads();
    }
    float rs = rsqrtf(red[0] / n + 1e-5f);
    if (t < n) {
        float r = d0 * rs * g[t] + bb[t];
        y[t] = relu ? fmaxf(r, 0.f) : r;
    }
    if (t + 256 < n) {
        float r = d1 * rs * g[t + 256] + bb[t + 256];
        y[t + 256] = relu ? fmaxf(r, 0.f) : r;
    }
}

// -------- embed finish: LN(g2)+relu+pos for tokens, cls row for l==0 ---------
__global__ void embed_finish(const float* __restrict__ tmp,   // [B*L, D] raw gemm2 out
                             const float* __restrict__ g, const float* __restrict__ bb,
                             const float* __restrict__ pos, const float* __restrict__ cls,
                             float* __restrict__ h) {
    int row = blockIdx.x;              // 0..B*LP-1
    int b = row / LP_, l = row % LP_;
    int t = threadIdx.x;               // 256
    float* out = h + (size_t)row * D_;
    if (l == 0) {
        if (t < D_) out[t] = cls[t];
        return;
    }
    const float* x = tmp + ((size_t)b * L_ + (l - 1)) * D_;
    float v0 = (t < D_) ? x[t] : 0.f;
    __shared__ float red[256];
    red[t] = v0;
    __syncthreads();
    for (int off = 128; off > 0; off >>= 1) {
        if (t < off) red[t] += red[t + off];
        __syncthreads();
    }
    float mean = red[0] / D_;
    __syncthreads();
    float d0 = (t < D_) ? v0 - mean : 0.f;
    red[t] = d0 * d0;
    __syncthreads();
    for (int off = 128; off > 0; off >>= 1) {
        if (t < off) red[t] += red[t + off];
        __syncthreads();
    }
    float rs = rsqrtf(red[0] / D_ + 1e-5f);
    if (t < D_) {
        float r = d0 * rs * g[t] + bb[t];
        out[t] = fmaxf(r, 0.f) + pos[(size_t)(l - 1) * D_ + t];
    }
}

// ---------------- attention: one wave per (b, h, q) --------------------------
__global__ void attn_kernel(const float* __restrict__ q, const float* __restrict__ k,
                            const float* __restrict__ v, const float* __restrict__ mask,
                            float* __restrict__ o) {
    int qi = blockIdx.x;   // 0..LP-1
    int hh = blockIdx.y;   // 0..H-1
    int b  = blockIdx.z;   // 0..B-1
    int lane = threadIdx.x; // 0..63
    const float* qrow = q + ((size_t)b * LP_ + qi) * D_ + hh * DK_;
    float qv[DK_];
    #pragma unroll
    for (int j = 0; j < DK_; j++) qv[j] = qrow[j];
    float m = -1e30f, l = 0.f, acc[DK_];
    #pragma unroll
    for (int j = 0; j < DK_; j++) acc[j] = 0.f;
    for (int kk = lane; kk < LP_; kk += 64) {
        const float* krow = k + ((size_t)b * LP_ + kk) * D_ + hh * DK_;
        float s = 0.f;
        #pragma unroll
        for (int j = 0; j < DK_; j++) s += qv[j] * krow[j];
        s *= SCALE_;
        if (mask[b * LP_ + kk] != 0.f) s = -10000.f;
        float nm = fmaxf(m, s);
        float f = __expf(m - nm);
        float p = __expf(s - nm);
        l = l * f + p;
        const float* vrow = v + ((size_t)b * LP_ + kk) * D_ + hh * DK_;
        #pragma unroll
        for (int j = 0; j < DK_; j++) acc[j] = acc[j] * f + p * vrow[j];
        m = nm;
    }
    // butterfly combine across the 64-lane wave
    for (int off = 32; off > 0; off >>= 1) {
        float m2 = __shfl_xor(m, off);
        float l2 = __shfl_xor(l, off);
        float nm = fmaxf(m, m2);
        float f1 = __expf(m - nm), f2 = __expf(m2 - nm);
        l = l * f1 + l2 * f2;
        #pragma unroll
        for (int j = 0; j < DK_; j++) {
            float a2 = __shfl_xor(acc[j], off);
            acc[j] = acc[j] * f1 + a2 * f2;
        }
        m = nm;
    }
    if (lane == 0) {
        float inv = 1.f / l;
        float* orow = o + ((size_t)b * LP_ + qi) * D_ + hh * DK_;
        #pragma unroll
        for (int j = 0; j < DK_; j++) orow[j] = acc[j] * inv;
    }
}

// ---------------- masked mean pool -------------------------------------------
__global__ void pool_kernel(const float* __restrict__ h, const float* __restrict__ mask,
                            float* __restrict__ pool) {
    int b = blockIdx.x;
    int d = threadIdx.x;
    if (d >= D_) return;
    float s = 0.f, c = 0.f;
    for (int l = 0; l < LP_; l++) {
        if (mask[b * LP_ + l] == 0.f) {
            s += h[((size_t)b * LP_ + l) * D_ + d];
            c += 1.f;
        }
    }
    pool[b * D_ + d] = s / c;
}

// ---------------- logits -----------------------------------------------------
__global__ void logits_kernel(const float* __restrict__ pool, const float* __restrict__ W,
                              const float* __restrict__ bias, float* __restrict__ out) {
    int idx = blockIdx.x * blockDim.x + threadIdx.x;
    if (idx >= B_ * NC_) return;
    int b = idx / NC_, n = idx - b * NC_;
    float s = bias[n];
    const float* p = pool + b * D_;
    for (int kk = 0; kk < D_; kk++) s += p[kk] * W[(size_t)kk * NC_ + n];
    out[idx] = s;
}

extern "C" void kernel_launch(void* const* d_in, const int* in_sizes, int n_in,
                              void* d_out, int out_size, void* d_ws, size_t ws_size,
                              hipStream_t stream) {
    const float* x        = (const float*)d_in[0];
    const float* pos      = (const float*)d_in[1];
    const float* cls      = (const float*)d_in[2];
    const float* e_W1     = (const float*)d_in[3];
    const float* e_b1     = (const float*)d_in[4];
    const float* e_g1     = (const float*)d_in[5];
    const float* e_bn1    = (const float*)d_in[6];
    const float* e_W2     = (const float*)d_in[7];
    const float* e_b2     = (const float*)d_in[8];
    const float* e_g2     = (const float*)d_in[9];
    const float* e_bn2    = (const float*)d_in[10];
    const float* ln1_g    = (const float*)d_in[11];
    const float* ln1_b    = (const float*)d_in[12];
    const float* Wq       = (const float*)d_in[13];
    const float* bq       = (const float*)d_in[14];
    const float* Wk       = (const float*)d_in[15];
    const float* bk       = (const float*)d_in[16];
    const float* Wv       = (const float*)d_in[17];
    const float* bv       = (const float*)d_in[18];
    const float* Wo       = (const float*)d_in[19];
    const float* bo       = (const float*)d_in[20];
    const float* ln2_g    = (const float*)d_in[21];
    const float* ln2_b    = (const float*)d_in[22];
    const float* W1       = (const float*)d_in[23];
    const float* b1       = (const float*)d_in[24];
    const float* W2       = (const float*)d_in[25];
    const float* b2       = (const float*)d_in[26];
    const float* logit_W  = (const float*)d_in[27];
    const float* logit_b  = (const float*)d_in[28];
    float* out = (float*)d_out;

    const size_t TOK  = (size_t)B_ * LP_;      // 8224
    const size_t HN   = TOK * D_;              // 1,973,760
    const size_t TN   = TOK * HID_;            // 3,947,520

    float* ws   = (float*)d_ws;
    float* mask = ws;                          // 8224
    float* h    = mask + 8224;
    float* y    = h + HN;
    float* q    = y + HN;
    float* k    = q + HN;
    float* v    = k + HN;
    float* o    = v + HN;
    float* t    = o + HN;                      // TN floats (also embed hidden)
    float* pl   = t + TN;                      // B*D

    const int BS = 256;
    auto blocks = [](size_t n) { return (int)((n + 255) / 256); };

    // mask
    mask_kernel<<<blocks(TOK), BS, 0, stream>>>(x, mask);
    // embed layer 1: [B*L,164] @ [164,480] -> t ; LN+relu in place
    gemm_kernel<<<blocks((size_t)B_ * L_ * HID_), BS, 0, stream>>>(
        x, e_W1, e_b1, t, B_ * L_, HID_, PD_, 0);
    ln_kernel<<<B_ * L_, BS, 0, stream>>>(t, t, e_g1, e_bn1, HID_, 1);
    // embed layer 2: [B*L,480] @ [480,240] -> y(raw) ; finish -> h
    gemm_kernel<<<blocks((size_t)B_ * L_ * D_), BS, 0, stream>>>(
        t, e_W2, e_b2, y, B_ * L_, D_, HID_, 0);
    embed_finish<<<(int)TOK, BS, 0, stream>>>(y, e_g2, e_bn2, pos, cls, h);

    for (int i = 0; i < NB_; i++) {
        const size_t wofs = (size_t)i * D_ * D_;
        // pre-norm attention
        ln_kernel<<<(int)TOK, BS, 0, stream>>>(h, y, ln1_g + i * D_, ln1_b + i * D_, D_, 0);
        gemm_kernel<<<blocks(HN), BS, 0, stream>>>(y, Wq + wofs, bq + i * D_, q,
                                                   (int)TOK, D_, D_, 0);
        gemm_kernel<<<blocks(HN), BS, 0, stream>>>(y, Wk + wofs, bk + i * D_, k,
                                                   (int)TOK, D_, D_, 0);
        gemm_kernel<<<blocks(HN), BS, 0, stream>>>(y, Wv + wofs, bv + i * D_, v,
                                                   (int)TOK, D_, D_, 0);
        attn_kernel<<<dim3(LP_, H_, B_), 64, 0, stream>>>(q, k, v, mask, o);
        gemm_kernel<<<blocks(HN), BS, 0, stream>>>(o, Wo + wofs, bo + i * D_, h,
                                                   (int)TOK, D_, D_, 2);
        // pre-norm FFN
        ln_kernel<<<(int)TOK, BS, 0, stream>>>(h, y, ln2_g + i * D_, ln2_b + i * D_, D_, 0);
        gemm_kernel<<<blocks(TN), BS, 0, stream>>>(y, W1 + (size_t)i * D_ * HID_,
                                                   b1 + i * HID_, t, (int)TOK, HID_, D_, 1);
        gemm_kernel<<<blocks(HN), BS, 0, stream>>>(t, W2 + (size_t)i * HID_ * D_,
                                                   b2 + i * D_, h, (int)TOK, D_, HID_, 2);
    }

    pool_kernel<<<B_, BS, 0, stream>>>(h, mask, pl);
    logits_kernel<<<blocks((size_t)B_ * NC_), BS, 0, stream>>>(pl, logit_W, logit_b, out);
}

// Round 2
// 3099.650 us; speedup vs baseline: 2.7419x; 2.7419x over previous
//
#include <hip/hip_runtime.h>
#include <hip/hip_bf16.h>
#include <math.h>

#define B_  32
#define L_  256
#define PD_ 164
#define D_  240
#define H_  16
#define NB_ 6
#define NC_ 250
#define DK_ 15
#define HID_ 480
#define LP_ 257            // L+1
#define SCALE_ 0.2581988897471611f   // 1/sqrt(15)

// ---------------- mask ----------------
__global__ void mask_kernel(const float* __restrict__ x, float* __restrict__ mask) {
    int idx = blockIdx.x * blockDim.x + threadIdx.x;
    if (idx >= B_ * LP_) return;
    int b = idx / LP_, l = idx % LP_;
    if (l == 0) { mask[idx] = 0.f; return; }
    const float* xr = x + ((size_t)b * L_ + (l - 1)) * PD_;
    float mx = -1e30f;
    for (int j = 0; j < PD_; j++) mx = fmaxf(mx, xr[j]);
    mask[idx] = (mx == 0.f) ? 1.f : 0.f;
}

// ---------------- tiled GEMM: C = A[M,K] @ B[K,N] (+bias)(relu)(accum) -------
// 128x64 tile, 256 threads, 8x4 per thread, K-tile 16.
// flags: 1 = relu, 2 = accumulate into C (residual)
__global__ __launch_bounds__(256)
void gemm_tiled(const float* __restrict__ A, const float* __restrict__ Bm,
                const float* __restrict__ bias, float* __restrict__ C,
                int M, int N, int K, int flags) {
    __shared__ float As[16][132];   // [k][m], padded stride
    __shared__ float Bs[16][64];    // [k][n]
    const int tid = threadIdx.x;
    const int bm = blockIdx.x * 128;
    const int bn = blockIdx.y * 64;
    const int tx = tid & 15;        // n
    const int ty = tid >> 4;        // m
    float acc[8][4];
    #pragma unroll
    for (int i = 0; i < 8; i++)
        #pragma unroll
        for (int j = 0; j < 4; j++) acc[i][j] = 0.f;

    const int arow  = tid >> 2;         // 0..63
    const int acol4 = (tid & 3) << 2;   // 0,4,8,12
    const int brow  = tid >> 4;         // 0..15
    const int bcol4 = (tid & 15) << 2;  // 0..60

    const int nkt = (K + 15) / 16;
    for (int kt = 0; kt < nkt; kt++) {
        const int k0 = kt * 16;
        // stage A (transpose to [k][m])
        #pragma unroll
        for (int half = 0; half < 2; half++) {
            int r  = arow + half * 64;
            int gm = bm + r;
            float4 av = make_float4(0.f, 0.f, 0.f, 0.f);
            if (gm < M && (k0 + acol4) < K)     // K % 4 == 0 for all uses
                av = *(const float4*)(A + (size_t)gm * K + k0 + acol4);
            As[acol4 + 0][r] = av.x;
            As[acol4 + 1][r] = av.y;
            As[acol4 + 2][r] = av.z;
            As[acol4 + 3][r] = av.w;
        }
        // stage B
        {
            int gk = k0 + brow, gn = bn + bcol4;
            float4 bv = make_float4(0.f, 0.f, 0.f, 0.f);
            if (gk < K && gn < N)               // N % 4 == 0 for all uses
                bv = *(const float4*)(Bm + (size_t)gk * N + gn);
            *(float4*)&Bs[brow][bcol4] = bv;
        }
        __syncthreads();
        #pragma unroll
        for (int kk = 0; kk < 16; kk++) {
            float4 b4 = *(const float4*)&Bs[kk][tx << 2];
            float4 a0 = *(const float4*)&As[kk][ty << 3];
            float4 a1 = *(const float4*)&As[kk][(ty << 3) + 4];
            float am[8] = {a0.x, a0.y, a0.z, a0.w, a1.x, a1.y, a1.z, a1.w};
            float bn4[4] = {b4.x, b4.y, b4.z, b4.w};
            #pragma unroll
            for (int i = 0; i < 8; i++)
                #pragma unroll
                for (int j = 0; j < 4; j++) acc[i][j] += am[i] * bn4[j];
        }
        __syncthreads();
    }
    // epilogue
    #pragma unroll
    for (int i = 0; i < 8; i++) {
        int m = bm + (ty << 3) + i;
        if (m >= M) continue;
        #pragma unroll
        for (int j = 0; j < 4; j++) {
            int n = bn + (tx << 2) + j;
            if (n >= N) continue;
            float s = acc[i][j];
            if (bias) s += bias[n];
            if (flags & 1) s = fmaxf(s, 0.f);
            size_t off = (size_t)m * N + n;
            if (flags & 2) C[off] += s; else C[off] = s;
        }
    }
}

// ---------------- row LayerNorm (row length n <= 512, block 256) -------------
__global__ void ln_kernel(const float* __restrict__ in, float* __restrict__ out,
                          const float* __restrict__ g, const float* __restrict__ bb,
                          int n, int relu) {
    int row = blockIdx.x;
    const float* x = in + (size_t)row * n;
    float* y = out + (size_t)row * n;
    int t = threadIdx.x;
    float v0 = (t < n) ? x[t] : 0.f;
    float v1 = (t + 256 < n) ? x[t + 256] : 0.f;
    __shared__ float red[256];
    red[t] = v0 + v1;
    __syncthreads();
    for (int off = 128; off > 0; off >>= 1) {
        if (t < off) red[t] += red[t + off];
        __syncthreads();
    }
    float mean = red[0] / n;
    __syncthreads();
    float d0 = (t < n) ? v0 - mean : 0.f;
    float d1 = (t + 256 < n) ? v1 - mean : 0.f;
    red[t] = d0 * d0 + d1 * d1;
    __syncthreads();
    for (int off = 128; off > 0; off >>= 1) {
        if (t < off) red[t] += red[t + off];
        __syncthreads();
    }
    float rs = rsqrtf(red[0] / n + 1e-5f);
    if (t < n) {
        float r = d0 * rs * g[t] + bb[t];
        y[t] = relu ? fmaxf(r, 0.f) : r;
    }
    if (t + 256 < n) {
        float r = d1 * rs * g[t + 256] + bb[t + 256];
        y[t + 256] = relu ? fmaxf(r, 0.f) : r;
    }
}

// -------- embed finish: LN(g2)+relu+pos for tokens, cls row for l==0 ---------
__global__ void embed_finish(const float* __restrict__ tmp,   // [B*L, D] raw gemm2 out
                             const float* __restrict__ g, const float* __restrict__ bb,
                             const float* __restrict__ pos, const float* __restrict__ cls,
                             float* __restrict__ h) {
    int row = blockIdx.x;              // 0..B*LP-1
    int b = row / LP_, l = row % LP_;
    int t = threadIdx.x;               // 256
    float* out = h + (size_t)row * D_;
    if (l == 0) {
        if (t < D_) out[t] = cls[t];
        return;
    }
    const float* x = tmp + ((size_t)b * L_ + (l - 1)) * D_;
    float v0 = (t < D_) ? x[t] : 0.f;
    __shared__ float red[256];
    red[t] = v0;
    __syncthreads();
    for (int off = 128; off > 0; off >>= 1) {
        if (t < off) red[t] += red[t + off];
        __syncthreads();
    }
    float mean = red[0] / D_;
    __syncthreads();
    float d0 = (t < D_) ? v0 - mean : 0.f;
    red[t] = d0 * d0;
    __syncthreads();
    for (int off = 128; off > 0; off >>= 1) {
        if (t < off) red[t] += red[t + off];
        __syncthreads();
    }
    float rs = rsqrtf(red[0] / D_ + 1e-5f);
    if (t < D_) {
        float r = d0 * rs * g[t] + bb[t];
        out[t] = fmaxf(r, 0.f) + pos[(size_t)(l - 1) * D_ + t];
    }
}

// ---------------- attention: one block per (b, h), K/V staged in LDS ---------
// One thread per query row; online softmax in registers.
__global__ __launch_bounds__(256)
void attn_kernel(const float* __restrict__ q, const float* __restrict__ k,
                 const float* __restrict__ v, const float* __restrict__ mask,
                 float* __restrict__ o) {
    const int hh = blockIdx.x;   // 0..H-1
    const int b  = blockIdx.y;   // 0..B-1
    const int tid = threadIdx.x;
    __shared__ float Ks[LP_][16];
    __shared__ float Vs[LP_][16];
    __shared__ float Ms[LP_];
    for (int i = tid; i < LP_ * 16; i += 256) {
        int row = i >> 4, c = i & 15;
        float kv = 0.f, vv = 0.f;
        if (c < DK_) {
            size_t base = ((size_t)b * LP_ + row) * D_ + hh * DK_ + c;
            kv = k[base];
            vv = v[base];
        }
        Ks[row][c] = kv;
        Vs[row][c] = vv;
    }
    for (int i = tid; i < LP_; i += 256) Ms[i] = mask[b * LP_ + i];
    __syncthreads();

    for (int qi = tid; qi < LP_; qi += 256) {
        const float* qrow = q + ((size_t)b * LP_ + qi) * D_ + hh * DK_;
        float qv[16];
        #pragma unroll
        for (int j = 0; j < 16; j++) qv[j] = (j < DK_) ? qrow[j] * SCALE_ : 0.f;
        float m = -1e30f, l = 0.f;
        float acc[16];
        #pragma unroll
        for (int j = 0; j < 16; j++) acc[j] = 0.f;
        for (int kk = 0; kk < LP_; kk++) {
            const float* kr = &Ks[kk][0];
            float s = 0.f;
            #pragma unroll
            for (int j = 0; j < 16; j++) s += qv[j] * kr[j];
            if (Ms[kk] != 0.f) s = -10000.f;
            float nm = fmaxf(m, s);
            float f = __expf(m - nm);
            float p = __expf(s - nm);
            l = l * f + p;
            const float* vr = &Vs[kk][0];
            #pragma unroll
            for (int j = 0; j < 16; j++) acc[j] = acc[j] * f + p * vr[j];
            m = nm;
        }
        float inv = 1.f / l;
        float* orow = o + ((size_t)b * LP_ + qi) * D_ + hh * DK_;
        #pragma unroll
        for (int j = 0; j < DK_; j++) orow[j] = acc[j] * inv;
    }
}

// ---------------- masked mean pool -------------------------------------------
__global__ void pool_kernel(const float* __restrict__ h, const float* __restrict__ mask,
                            float* __restrict__ pool) {
    int b = blockIdx.x;
    int d = threadIdx.x;
    if (d >= D_) return;
    float s = 0.f, c = 0.f;
    for (int l = 0; l < LP_; l++) {
        if (mask[b * LP_ + l] == 0.f) {
            s += h[((size_t)b * LP_ + l) * D_ + d];
            c += 1.f;
        }
    }
    pool[b * D_ + d] = s / c;
}

// ---------------- logits -----------------------------------------------------
__global__ void logits_kernel(const float* __restrict__ pool, const float* __restrict__ W,
                              const float* __restrict__ bias, float* __restrict__ out) {
    int idx = blockIdx.x * blockDim.x + threadIdx.x;
    if (idx >= B_ * NC_) return;
    int b = idx / NC_, n = idx - b * NC_;
    float s = bias[n];
    const float* p = pool + b * D_;
    for (int kk = 0; kk < D_; kk++) s += p[kk] * W[(size_t)kk * NC_ + n];
    out[idx] = s;
}

extern "C" void kernel_launch(void* const* d_in, const int* in_sizes, int n_in,
                              void* d_out, int out_size, void* d_ws, size_t ws_size,
                              hipStream_t stream) {
    const float* x        = (const float*)d_in[0];
    const float* pos      = (const float*)d_in[1];
    const float* cls      = (const float*)d_in[2];
    const float* e_W1     = (const float*)d_in[3];
    const float* e_b1     = (const float*)d_in[4];
    const float* e_g1     = (const float*)d_in[5];
    const float* e_bn1    = (const float*)d_in[6];
    const float* e_W2     = (const float*)d_in[7];
    const float* e_b2     = (const float*)d_in[8];
    const float* e_g2     = (const float*)d_in[9];
    const float* e_bn2    = (const float*)d_in[10];
    const float* ln1_g    = (const float*)d_in[11];
    const float* ln1_b    = (const float*)d_in[12];
    const float* Wq       = (const float*)d_in[13];
    const float* bq       = (const float*)d_in[14];
    const float* Wk       = (const float*)d_in[15];
    const float* bk       = (const float*)d_in[16];
    const float* Wv       = (const float*)d_in[17];
    const float* bv       = (const float*)d_in[18];
    const float* Wo       = (const float*)d_in[19];
    const float* bo       = (const float*)d_in[20];
    const float* ln2_g    = (const float*)d_in[21];
    const float* ln2_b    = (const float*)d_in[22];
    const float* W1       = (const float*)d_in[23];
    const float* b1       = (const float*)d_in[24];
    const float* W2       = (const float*)d_in[25];
    const float* b2       = (const float*)d_in[26];
    const float* logit_W  = (const float*)d_in[27];
    const float* logit_b  = (const float*)d_in[28];
    float* out = (float*)d_out;

    const size_t TOK  = (size_t)B_ * LP_;      // 8224
    const size_t HN   = TOK * D_;              // 1,973,760
    const size_t TN   = TOK * HID_;            // 3,947,520

    float* ws   = (float*)d_ws;
    float* mask = ws;                          // 8224
    float* h    = mask + 8224;
    float* y    = h + HN;
    float* q    = y + HN;
    float* k    = q + HN;
    float* v    = k + HN;
    float* o    = v + HN;
    float* t    = o + HN;                      // TN floats (also embed hidden)
    float* pl   = t + TN;                      // B*D

    const int BS = 256;
    auto blocks = [](size_t n) { return (int)((n + 255) / 256); };
    auto ggrid = [](int M, int N) { return dim3((M + 127) / 128, (N + 63) / 64); };

    // mask
    mask_kernel<<<blocks(TOK), BS, 0, stream>>>(x, mask);
    // embed layer 1: [B*L,164] @ [164,480] -> t ; LN+relu in place
    gemm_tiled<<<ggrid(B_ * L_, HID_), BS, 0, stream>>>(x, e_W1, e_b1, t,
                                                        B_ * L_, HID_, PD_, 0);
    ln_kernel<<<B_ * L_, BS, 0, stream>>>(t, t, e_g1, e_bn1, HID_, 1);
    // embed layer 2: [B*L,480] @ [480,240] -> y(raw) ; finish -> h
    gemm_tiled<<<ggrid(B_ * L_, D_), BS, 0, stream>>>(t, e_W2, e_b2, y,
                                                      B_ * L_, D_, HID_, 0);
    embed_finish<<<(int)TOK, BS, 0, stream>>>(y, e_g2, e_bn2, pos, cls, h);

    for (int i = 0; i < NB_; i++) {
        const size_t wofs = (size_t)i * D_ * D_;
        // pre-norm attention
        ln_kernel<<<(int)TOK, BS, 0, stream>>>(h, y, ln1_g + i * D_, ln1_b + i * D_, D_, 0);
        gemm_tiled<<<ggrid((int)TOK, D_), BS, 0, stream>>>(y, Wq + wofs, bq + i * D_, q,
                                                           (int)TOK, D_, D_, 0);
        gemm_tiled<<<ggrid((int)TOK, D_), BS, 0, stream>>>(y, Wk + wofs, bk + i * D_, k,
                                                           (int)TOK, D_, D_, 0);
        gemm_tiled<<<ggrid((int)TOK, D_), BS, 0, stream>>>(y, Wv + wofs, bv + i * D_, v,
                                                           (int)TOK, D_, D_, 0);
        attn_kernel<<<dim3(H_, B_), BS, 0, stream>>>(q, k, v, mask, o);
        gemm_tiled<<<ggrid((int)TOK, D_), BS, 0, stream>>>(o, Wo + wofs, bo + i * D_, h,
                                                           (int)TOK, D_, D_, 2);
        // pre-norm FFN
        ln_kernel<<<(int)TOK, BS, 0, stream>>>(h, y, ln2_g + i * D_, ln2_b + i * D_, D_, 0);
        gemm_tiled<<<ggrid((int)TOK, HID_), BS, 0, stream>>>(y, W1 + (size_t)i * D_ * HID_,
                                                             b1 + i * HID_, t,
                                                             (int)TOK, HID_, D_, 1);
        gemm_tiled<<<ggrid((int)TOK, D_), BS, 0, stream>>>(t, W2 + (size_t)i * HID_ * D_,
                                                           b2 + i * D_, h,
                                                           (int)TOK, D_, HID_, 2);
    }

    pool_kernel<<<B_, BS, 0, stream>>>(h, mask, pl);
    logits_kernel<<<blocks((size_t)B_ * NC_), BS, 0, stream>>>(pl, logit_W, logit_b, out);
}

// Round 3
// 1794.023 us; speedup vs baseline: 4.7373x; 1.7278x over previous
//
#include <hip/hip_runtime.h>
#include <math.h>

#define B_  32
#define L_  256
#define PD_ 164
#define D_  240
#define H_  16
#define NB_ 6
#define NC_ 250
#define DK_ 15
#define HID_ 480
#define LP_ 257
#define SCALE_ 0.2581988897471611f   // 1/sqrt(15)
#define LOG2E_ 1.4426950408889634f

typedef __attribute__((ext_vector_type(8))) short bf16x8;
typedef __attribute__((ext_vector_type(4))) float f32x4;
typedef _Float16 h2 __attribute__((ext_vector_type(2)));

static __device__ inline unsigned short f2bf(float x) {
    unsigned u = __builtin_bit_cast(unsigned, x);
    u += 0x7FFFu + ((u >> 16) & 1u);     // RNE (finite values only)
    return (unsigned short)(u >> 16);
}

// ---------------- mask ----------------
__global__ void mask_kernel(const float* __restrict__ x, float* __restrict__ mask) {
    int idx = blockIdx.x * blockDim.x + threadIdx.x;
    if (idx >= B_ * LP_) return;
    int b = idx / LP_, l = idx % LP_;
    if (l == 0) { mask[idx] = 0.f; return; }
    const float* xr = x + ((size_t)b * L_ + (l - 1)) * PD_;
    float mx = -1e30f;
    for (int j = 0; j < PD_; j++) mx = fmaxf(mx, xr[j]);
    mask[idx] = (mx == 0.f) ? 1.f : 0.f;
}

// --------- weight pretranspose: fp32 [batch][K][N] -> bf16 [batch][N][Kpad] --
__global__ void pretrans(const float* __restrict__ W, unsigned short* __restrict__ out,
                         int K, int N, int Kpad, long sstride, long dstride) {
    int n = blockIdx.x, bb = blockIdx.y;
    const float* src = W + (size_t)bb * sstride;
    unsigned short* dst = out + (size_t)bb * dstride + (size_t)n * Kpad;
    for (int k = threadIdx.x; k < Kpad; k += 64)
        dst[k] = f2bf(k < K ? src[(size_t)k * N + n] : 0.f);
}

// --------- init c==15 lanes of packed q/k/v (mask folding) -------------------
__global__ void attn_init(const float* __restrict__ mask, _Float16* __restrict__ qp,
                          _Float16* __restrict__ kp, _Float16* __restrict__ vp) {
    int idx = blockIdx.x * blockDim.x + threadIdx.x;   // (b*H+h)*LP + l
    if (idx >= B_ * H_ * LP_) return;
    int l = idx % LP_;
    int b = idx / (H_ * LP_);
    qp[(size_t)idx * 16 + 15] = (_Float16)LOG2E_;
    kp[(size_t)idx * 16 + 15] = (_Float16)((mask[b * LP_ + l] != 0.f) ? -10000.f : 0.f);
    vp[(size_t)idx * 16 + 15] = (_Float16)0.f;
}

// --------- pack bq|bk|bv per layer into one 720-vector -----------------------
__global__ void pack_bias(const float* __restrict__ bq, const float* __restrict__ bk,
                          const float* __restrict__ bv, float* __restrict__ b720) {
    int i = blockIdx.x;
    for (int n = threadIdx.x; n < 720; n += 256) {
        float v = (n < 240) ? bq[i * 240 + n]
                : (n < 480) ? bk[i * 240 + n - 240]
                            : bv[i * 240 + n - 480];
        b720[i * 720 + n] = v;
    }
}

// ---------------- MFMA GEMM: C = A[M,K]fp32 @ Bt[N,Kpad]bf16 -----------------
// tile 128x64, 256 threads (4 waves 2x2), K-step 32.
// flags: 1 relu, 2 accumulate, 4 QKV-packed-f16 epilogue (N must be 720)
__global__ __launch_bounds__(256)
void gemm_mfma(const float* __restrict__ A, const unsigned short* __restrict__ Bt,
               const float* __restrict__ bias, float* __restrict__ C,
               _Float16* __restrict__ qp, _Float16* __restrict__ kp,
               _Float16* __restrict__ vp,
               int M, int N, int K, int Kpad, int flags)
{
    __shared__ unsigned short As[128 * 40];   // [m][k], stride 40 (pad 8)
    __shared__ unsigned short Bs[64 * 40];    // [n][k], stride 40
    const int tid = threadIdx.x;
    const int bm = blockIdx.x * 128;
    const int bn = blockIdx.y * 64;
    const int wave = tid >> 6, lane = tid & 63;
    const int wm = (wave & 1) * 64, wn = (wave >> 1) * 32;
    const int lq = lane >> 4, lr = lane & 15;
    f32x4 acc[4][2];
    #pragma unroll
    for (int i = 0; i < 4; i++)
        #pragma unroll
        for (int j = 0; j < 2; j++) acc[i][j] = (f32x4){0.f, 0.f, 0.f, 0.f};

    const int ar = tid >> 1;            // A row 0..127 (2 threads/row)
    const int ac = (tid & 1) << 4;      // col base 0/16
    const int brow = tid >> 2;          // B n-row 0..63
    const int bcol = (tid & 3) << 3;    // k base 0,8,16,24

    const int nkt = (K + 31) >> 5;
    for (int kt = 0; kt < nkt; kt++) {
        const int k0 = kt << 5;
        // ---- stage A (fp32 -> bf16) ----
        {
            const int gm = bm + ar;
            const int kb = k0 + ac;
            float v[16];
            if (gm < M && kb + 16 <= K) {
                const float* src = A + (size_t)gm * K + kb;
                f32x4 f0 = *(const f32x4*)(src);
                f32x4 f1 = *(const f32x4*)(src + 4);
                f32x4 f2 = *(const f32x4*)(src + 8);
                f32x4 f3 = *(const f32x4*)(src + 12);
                v[0]=f0.x; v[1]=f0.y; v[2]=f0.z; v[3]=f0.w;
                v[4]=f1.x; v[5]=f1.y; v[6]=f1.z; v[7]=f1.w;
                v[8]=f2.x; v[9]=f2.y; v[10]=f2.z; v[11]=f2.w;
                v[12]=f3.x; v[13]=f3.y; v[14]=f3.z; v[15]=f3.w;
            } else if (gm < M) {
                #pragma unroll
                for (int j = 0; j < 16; j++) {
                    int kk = kb + j;
                    v[j] = (kk < K) ? A[(size_t)gm * K + kk] : 0.f;
                }
            } else {
                #pragma unroll
                for (int j = 0; j < 16; j++) v[j] = 0.f;
            }
            bf16x8 p0, p1;
            #pragma unroll
            for (int j = 0; j < 8; j++) { p0[j] = (short)f2bf(v[j]); p1[j] = (short)f2bf(v[8 + j]); }
            *(bf16x8*)&As[ar * 40 + ac] = p0;
            *(bf16x8*)&As[ar * 40 + ac + 8] = p1;
        }
        // ---- stage B (bf16 copy) ----
        {
            const int gn = bn + brow;
            uint4 bv = {0u, 0u, 0u, 0u};
            if (gn < N) bv = *(const uint4*)(Bt + (size_t)gn * Kpad + k0 + bcol);
            *(uint4*)&Bs[brow * 40 + bcol] = bv;
        }
        __syncthreads();
        bf16x8 af[4], bfr[2];
        #pragma unroll
        for (int i = 0; i < 4; i++)
            af[i] = *(const bf16x8*)&As[(wm + i * 16 + lr) * 40 + lq * 8];
        #pragma unroll
        for (int j = 0; j < 2; j++)
            bfr[j] = *(const bf16x8*)&Bs[(wn + j * 16 + lr) * 40 + lq * 8];
        #pragma unroll
        for (int i = 0; i < 4; i++)
            #pragma unroll
            for (int j = 0; j < 2; j++)
                acc[i][j] = __builtin_amdgcn_mfma_f32_16x16x32_bf16(af[i], bfr[j], acc[i][j], 0, 0, 0);
        __syncthreads();
    }

    // ---- epilogue ----
    if (flags & 4) {
        #pragma unroll
        for (int j = 0; j < 2; j++) {
            int n = bn + wn + j * 16 + lr;
            if (n >= N) continue;
            int which = n / 240;
            int rem = n - which * 240;
            int hh = rem / 15;
            int c = rem - hh * 15;
            _Float16* dst = (which == 0) ? qp : (which == 1) ? kp : vp;
            float bias_n = bias[n];
            float mult = (which == 0) ? (SCALE_ * LOG2E_) : 1.f;
            #pragma unroll
            for (int i = 0; i < 4; i++)
                #pragma unroll
                for (int r = 0; r < 4; r++) {
                    int m = bm + wm + i * 16 + lq * 4 + r;
                    if (m >= M) continue;
                    float s = (acc[i][j][r] + bias_n) * mult;
                    int b = m / LP_, l = m - b * LP_;
                    dst[(((size_t)b * H_ + hh) * LP_ + l) * 16 + c] = (_Float16)s;
                }
        }
    } else {
        #pragma unroll
        for (int i = 0; i < 4; i++)
            #pragma unroll
            for (int j = 0; j < 2; j++) {
                int n = bn + wn + j * 16 + lr;
                if (n >= N) continue;
                float bias_n = bias ? bias[n] : 0.f;
                #pragma unroll
                for (int r = 0; r < 4; r++) {
                    int m = bm + wm + i * 16 + lq * 4 + r;
                    if (m >= M) continue;
                    float s = acc[i][j][r] + bias_n;
                    if (flags & 1) s = fmaxf(s, 0.f);
                    size_t off = (size_t)m * N + n;
                    if (flags & 2) C[off] += s; else C[off] = s;
                }
            }
    }
}

// ---------------- row LayerNorm (row length n <= 512, block 256) -------------
__global__ void ln_kernel(const float* __restrict__ in, float* __restrict__ out,
                          const float* __restrict__ g, const float* __restrict__ bb,
                          int n, int relu) {
    int row = blockIdx.x;
    const float* x = in + (size_t)row * n;
    float* y = out + (size_t)row * n;
    int t = threadIdx.x;
    float v0 = (t < n) ? x[t] : 0.f;
    float v1 = (t + 256 < n) ? x[t + 256] : 0.f;
    __shared__ float red[256];
    red[t] = v0 + v1;
    __syncthreads();
    for (int off = 128; off > 0; off >>= 1) {
        if (t < off) red[t] += red[t + off];
        __syncthreads();
    }
    float mean = red[0] / n;
    __syncthreads();
    float d0 = (t < n) ? v0 - mean : 0.f;
    float d1 = (t + 256 < n) ? v1 - mean : 0.f;
    red[t] = d0 * d0 + d1 * d1;
    __syncthreads();
    for (int off = 128; off > 0; off >>= 1) {
        if (t < off) red[t] += red[t + off];
        __syncthreads();
    }
    float rs = rsqrtf(red[0] / n + 1e-5f);
    if (t < n) {
        float r = d0 * rs * g[t] + bb[t];
        y[t] = relu ? fmaxf(r, 0.f) : r;
    }
    if (t + 256 < n) {
        float r = d1 * rs * g[t + 256] + bb[t + 256];
        y[t + 256] = relu ? fmaxf(r, 0.f) : r;
    }
}

// -------- embed finish: LN(g2)+relu+pos for tokens, cls row for l==0 ---------
__global__ void embed_finish(const float* __restrict__ tmp,
                             const float* __restrict__ g, const float* __restrict__ bb,
                             const float* __restrict__ pos, const float* __restrict__ cls,
                             float* __restrict__ h) {
    int row = blockIdx.x;
    int b = row / LP_, l = row % LP_;
    int t = threadIdx.x;
    float* out = h + (size_t)row * D_;
    if (l == 0) {
        if (t < D_) out[t] = cls[t];
        return;
    }
    const float* x = tmp + ((size_t)b * L_ + (l - 1)) * D_;
    float v0 = (t < D_) ? x[t] : 0.f;
    __shared__ float red[256];
    red[t] = v0;
    __syncthreads();
    for (int off = 128; off > 0; off >>= 1) {
        if (t < off) red[t] += red[t + off];
        __syncthreads();
    }
    float mean = red[0] / D_;
    __syncthreads();
    float d0 = (t < D_) ? v0 - mean : 0.f;
    red[t] = d0 * d0;
    __syncthreads();
    for (int off = 128; off > 0; off >>= 1) {
        if (t < off) red[t] += red[t + off];
        __syncthreads();
    }
    float rs = rsqrtf(red[0] / D_ + 1e-5f);
    if (t < D_) {
        float r = d0 * rs * g[t] + bb[t];
        out[t] = fmaxf(r, 0.f) + pos[(size_t)(l - 1) * D_ + t];
    }
}

// ---------------- attention: f16 K/V in LDS, thread-per-query ----------------
// grid (H, B, 5), 64 threads. q pre-scaled by SCALE*log2e; mask folded into
// k[15] (-10000) * q[15] (log2e) so exp2 underflows to 0 for masked keys.
__global__ __launch_bounds__(64)
void attn_kernel(const _Float16* __restrict__ qp, const _Float16* __restrict__ kp,
                 const _Float16* __restrict__ vp, float* __restrict__ o)
{
    const int hh = blockIdx.x, b = blockIdx.y, z = blockIdx.z;
    const int tid = threadIdx.x;
    __shared__ unsigned int Ks[LP_ * 8];
    __shared__ unsigned int Vs[LP_ * 8];
    const size_t base = ((size_t)b * H_ + hh) * LP_ * 16;
    const uint4* ksrc = (const uint4*)(kp + base);
    const uint4* vsrc = (const uint4*)(vp + base);
    for (int i = tid; i < LP_ * 2; i += 64) {
        ((uint4*)Ks)[i] = ksrc[i];
        ((uint4*)Vs)[i] = vsrc[i];
    }
    __syncthreads();
    const int qi = z * 64 + tid;
    if (qi >= LP_) return;
    const unsigned int* qsrc = (const unsigned int*)(qp + base + (size_t)qi * 16);
    unsigned int qu[8];
    #pragma unroll
    for (int j = 0; j < 8; j++) qu[j] = qsrc[j];
    float l = 0.f;
    float acc[16];
    #pragma unroll
    for (int j = 0; j < 16; j++) acc[j] = 0.f;
    for (int kk = 0; kk < LP_; kk++) {
        const unsigned int* kr = &Ks[kk * 8];
        float s = 0.f;
        #pragma unroll
        for (int j = 0; j < 8; j++)
            s = __builtin_amdgcn_fdot2(__builtin_bit_cast(h2, qu[j]),
                                       __builtin_bit_cast(h2, kr[j]), s, false);
        float p = exp2f(s);
        l += p;
        const unsigned int* vr = &Vs[kk * 8];
        #pragma unroll
        for (int j = 0; j < 8; j++) {
            h2 vv = __builtin_bit_cast(h2, vr[j]);
            acc[2 * j]     += p * (float)vv.x;
            acc[2 * j + 1] += p * (float)vv.y;
        }
    }
    float inv = 1.f / l;
    float* orow = o + ((size_t)(b * LP_ + qi)) * D_ + hh * DK_;
    #pragma unroll
    for (int j = 0; j < DK_; j++) orow[j] = acc[j] * inv;
}

// ---------------- masked mean pool -------------------------------------------
__global__ void pool_kernel(const float* __restrict__ h, const float* __restrict__ mask,
                            float* __restrict__ pool) {
    int b = blockIdx.x;
    int d = threadIdx.x;
    if (d >= D_) return;
    float s = 0.f, c = 0.f;
    for (int l = 0; l < LP_; l++) {
        if (mask[b * LP_ + l] == 0.f) {
            s += h[((size_t)b * LP_ + l) * D_ + d];
            c += 1.f;
        }
    }
    pool[b * D_ + d] = s / c;
}

// ---------------- logits -----------------------------------------------------
__global__ void logits_kernel(const float* __restrict__ pool, const float* __restrict__ W,
                              const float* __restrict__ bias, float* __restrict__ out) {
    int idx = blockIdx.x * blockDim.x + threadIdx.x;
    if (idx >= B_ * NC_) return;
    int b = idx / NC_, n = idx - b * NC_;
    float s = bias[n];
    const float* p = pool + b * D_;
    for (int kk = 0; kk < D_; kk++) s += p[kk] * W[(size_t)kk * NC_ + n];
    out[idx] = s;
}

extern "C" void kernel_launch(void* const* d_in, const int* in_sizes, int n_in,
                              void* d_out, int out_size, void* d_ws, size_t ws_size,
                              hipStream_t stream) {
    const float* x        = (const float*)d_in[0];
    const float* pos      = (const float*)d_in[1];
    const float* cls      = (const float*)d_in[2];
    const float* e_W1     = (const float*)d_in[3];
    const float* e_b1     = (const float*)d_in[4];
    const float* e_g1     = (const float*)d_in[5];
    const float* e_bn1    = (const float*)d_in[6];
    const float* e_W2     = (const float*)d_in[7];
    const float* e_b2     = (const float*)d_in[8];
    const float* e_g2     = (const float*)d_in[9];
    const float* e_bn2    = (const float*)d_in[10];
    const float* ln1_g    = (const float*)d_in[11];
    const float* ln1_b    = (const float*)d_in[12];
    const float* Wq       = (const float*)d_in[13];
    const float* bq       = (const float*)d_in[14];
    const float* Wk       = (const float*)d_in[15];
    const float* bk       = (const float*)d_in[16];
    const float* Wv       = (const float*)d_in[17];
    const float* bv       = (const float*)d_in[18];
    const float* Wo       = (const float*)d_in[19];
    const float* bo       = (const float*)d_in[20];
    const float* ln2_g    = (const float*)d_in[21];
    const float* ln2_b    = (const float*)d_in[22];
    const float* W1       = (const float*)d_in[23];
    const float* b1       = (const float*)d_in[24];
    const float* W2       = (const float*)d_in[25];
    const float* b2       = (const float*)d_in[26];
    const float* logit_W  = (const float*)d_in[27];
    const float* logit_b  = (const float*)d_in[28];
    float* out = (float*)d_out;

    const size_t TOK = (size_t)B_ * LP_;       // 8224
    const size_t HN  = TOK * D_;               // 1,973,760
    const size_t TN  = TOK * HID_;             // 3,947,520

    float* ws    = (float*)d_ws;
    float* mask  = ws;                 size_t cur = 8224;
    float* h     = ws + cur;           cur += HN;
    float* y     = ws + cur;           cur += HN;
    float* o     = ws + cur;           cur += HN;
    float* t     = ws + cur;           cur += TN;
    float* pl    = ws + cur;           cur += 7680;
    float* b720  = ws + cur;           cur += 4320;
    unsigned short* sh = (unsigned short*)(ws + cur);
    unsigned short* We1  = sh;                 size_t sc = (size_t)480 * 192;
    unsigned short* We2  = sh + sc;            sc += (size_t)240 * 480;
    unsigned short* Wqkv = sh + sc;            sc += (size_t)6 * 720 * 256;
    unsigned short* WoT  = sh + sc;            sc += (size_t)6 * 240 * 256;
    unsigned short* W1T  = sh + sc;            sc += (size_t)6 * 480 * 256;
    unsigned short* W2T  = sh + sc;            sc += (size_t)6 * 240 * 480;
    _Float16* qp = (_Float16*)(sh + sc);
    _Float16* kp = qp + (size_t)B_ * H_ * LP_ * 16;
    _Float16* vp = kp + (size_t)B_ * H_ * LP_ * 16;

    const int BS = 256;
    auto blocks = [](size_t n) { return (int)((n + 255) / 256); };

    // mask + packed-qkv c15 init + bias packing
    mask_kernel<<<blocks(TOK), BS, 0, stream>>>(x, mask);
    attn_init<<<blocks((size_t)B_ * H_ * LP_), BS, 0, stream>>>(mask, qp, kp, vp);
    pack_bias<<<NB_, BS, 0, stream>>>(bq, bk, bv, b720);

    // weight pretranspose (fp32 -> bf16 [N][Kpad])
    pretrans<<<dim3(480, 1), 64, 0, stream>>>(e_W1, We1, PD_, 480, 192, 0, 0);
    pretrans<<<dim3(240, 1), 64, 0, stream>>>(e_W2, We2, 480, 240, 480, 0, 0);
    pretrans<<<dim3(240, NB_), 64, 0, stream>>>(Wq, Wqkv,             240, 240, 256, 240*240, 720*256);
    pretrans<<<dim3(240, NB_), 64, 0, stream>>>(Wk, Wqkv + 240*256,   240, 240, 256, 240*240, 720*256);
    pretrans<<<dim3(240, NB_), 64, 0, stream>>>(Wv, Wqkv + 480*256,   240, 240, 256, 240*240, 720*256);
    pretrans<<<dim3(240, NB_), 64, 0, stream>>>(Wo, WoT,              240, 240, 256, 240*240, 240*256);
    pretrans<<<dim3(480, NB_), 64, 0, stream>>>(W1, W1T,              240, 480, 256, 240*480, 480*256);
    pretrans<<<dim3(240, NB_), 64, 0, stream>>>(W2, W2T,              480, 240, 480, 480*240, 240*480);

    // embed
    gemm_mfma<<<dim3(64, 8), BS, 0, stream>>>(x, We1, e_b1, t, nullptr, nullptr, nullptr,
                                              B_ * L_, 480, PD_, 192, 0);
    ln_kernel<<<B_ * L_, BS, 0, stream>>>(t, t, e_g1, e_bn1, HID_, 1);
    gemm_mfma<<<dim3(64, 4), BS, 0, stream>>>(t, We2, e_b2, y, nullptr, nullptr, nullptr,
                                              B_ * L_, D_, 480, 480, 0);
    embed_finish<<<(int)TOK, BS, 0, stream>>>(y, e_g2, e_bn2, pos, cls, h);

    for (int i = 0; i < NB_; i++) {
        // pre-norm attention
        ln_kernel<<<(int)TOK, BS, 0, stream>>>(h, y, ln1_g + i * D_, ln1_b + i * D_, D_, 0);
        gemm_mfma<<<dim3(65, 12), BS, 0, stream>>>(y, Wqkv + (size_t)i * 720 * 256,
                                                   b720 + i * 720, nullptr, qp, kp, vp,
                                                   (int)TOK, 720, D_, 256, 4);
        attn_kernel<<<dim3(H_, B_, 5), 64, 0, stream>>>(qp, kp, vp, o);
        gemm_mfma<<<dim3(65, 4), BS, 0, stream>>>(o, WoT + (size_t)i * 240 * 256,
                                                  bo + i * D_, h, nullptr, nullptr, nullptr,
                                                  (int)TOK, D_, D_, 256, 2);
        // pre-norm FFN
        ln_kernel<<<(int)TOK, BS, 0, stream>>>(h, y, ln2_g + i * D_, ln2_b + i * D_, D_, 0);
        gemm_mfma<<<dim3(65, 8), BS, 0, stream>>>(y, W1T + (size_t)i * 480 * 256,
                                                  b1 + i * HID_, t, nullptr, nullptr, nullptr,
                                                  (int)TOK, HID_, D_, 256, 1);
        gemm_mfma<<<dim3(65, 4), BS, 0, stream>>>(t, W2T + (size_t)i * 240 * 480,
                                                  b2 + i * D_, h, nullptr, nullptr, nullptr,
                                                  (int)TOK, D_, HID_, 480, 2);
    }

    pool_kernel<<<B_, BS, 0, stream>>>(h, mask, pl);
    logits_kernel<<<blocks((size_t)B_ * NC_), BS, 0, stream>>>(pl, logit_W, logit_b, out);
}

// Round 4
// 1376.185 us; speedup vs baseline: 6.1756x; 1.3036x over previous
//
#include <hip/hip_runtime.h>
#include <math.h>

#define B_  32
#define L_  256
#define PD_ 164
#define D_  240
#define H_  16
#define NB_ 6
#define NC_ 250
#define DK_ 15
#define HID_ 480
#define LP_ 257
#define SCALE_ 0.2581988897471611f   // 1/sqrt(15)
#define LOG2E_ 1.4426950408889634f

typedef __attribute__((ext_vector_type(8))) short bf16x8;
typedef __attribute__((ext_vector_type(4))) float f32x4;
typedef _Float16 h2 __attribute__((ext_vector_type(2)));

static __device__ inline unsigned short f2bf(float x) {
    unsigned u = __builtin_bit_cast(unsigned, x);
    u += 0x7FFFu + ((u >> 16) & 1u);     // RNE (finite values only)
    return (unsigned short)(u >> 16);
}
static __device__ inline float fdot2u(unsigned a, unsigned b, float c) {
    return __builtin_amdgcn_fdot2(__builtin_bit_cast(h2, a),
                                  __builtin_bit_cast(h2, b), c, false);
}
static __device__ inline float h2lo(unsigned u) { h2 v = __builtin_bit_cast(h2, u); return (float)v.x; }
static __device__ inline float h2hi(unsigned u) { h2 v = __builtin_bit_cast(h2, u); return (float)v.y; }

// ---------------- mask ----------------
__global__ void mask_kernel(const float* __restrict__ x, float* __restrict__ mask) {
    int idx = blockIdx.x * blockDim.x + threadIdx.x;
    if (idx >= B_ * LP_) return;
    int b = idx / LP_, l = idx % LP_;
    if (l == 0) { mask[idx] = 0.f; return; }
    const float* xr = x + ((size_t)b * L_ + (l - 1)) * PD_;
    float mx = -1e30f;
    for (int j = 0; j < PD_; j++) mx = fmaxf(mx, xr[j]);
    mask[idx] = (mx == 0.f) ? 1.f : 0.f;
}

// --------- x fp32 [8192][164] -> bf16 [8192][192] (zero pad) -----------------
__global__ void cvt_x(const float* __restrict__ x, unsigned short* __restrict__ xbf) {
    int row = blockIdx.x;
    const float* src = x + (size_t)row * PD_;
    unsigned short* dst = xbf + (size_t)row * 192;
    for (int k = threadIdx.x; k < 192; k += 64)
        dst[k] = f2bf(k < PD_ ? src[k] : 0.f);
}

// --------- weight pretranspose: fp32 [batch][K][N] -> bf16 [batch][N][Kpad] --
__global__ void pretrans(const float* __restrict__ W, unsigned short* __restrict__ out,
                         int K, int N, int Kpad, long sstride, long dstride) {
    int n = blockIdx.x, bb = blockIdx.y;
    const float* src = W + (size_t)bb * sstride;
    unsigned short* dst = out + (size_t)bb * dstride + (size_t)n * Kpad;
    for (int k = threadIdx.x; k < Kpad; k += 64)
        dst[k] = f2bf(k < K ? src[(size_t)k * N + n] : 0.f);
}

// --------- init c==15 lanes of packed q/k/v (mask folding) -------------------
__global__ void attn_init(const float* __restrict__ mask, _Float16* __restrict__ qp,
                          _Float16* __restrict__ kp, _Float16* __restrict__ vp) {
    int idx = blockIdx.x * blockDim.x + threadIdx.x;   // (b*H+h)*LP + l
    if (idx >= B_ * H_ * LP_) return;
    int l = idx % LP_;
    int b = idx / (H_ * LP_);
    qp[(size_t)idx * 16 + 15] = (_Float16)LOG2E_;
    kp[(size_t)idx * 16 + 15] = (_Float16)((mask[b * LP_ + l] != 0.f) ? -10000.f : 0.f);
    vp[(size_t)idx * 16 + 15] = (_Float16)0.f;
}

// --------- pack bq|bk|bv per layer into one 720-vector -----------------------
__global__ void pack_bias(const float* __restrict__ bq, const float* __restrict__ bk,
                          const float* __restrict__ bv, float* __restrict__ b720) {
    int i = blockIdx.x;
    for (int n = threadIdx.x; n < 720; n += 256) {
        float v = (n < 240) ? bq[i * 240 + n]
                : (n < 480) ? bk[i * 240 + n - 240]
                            : bv[i * 240 + n - 480];
        b720[i * 720 + n] = v;
    }
}

// ---------------- MFMA GEMM: C = A[M,Kpad]bf16 @ Bt[N,Kpad]bf16 --------------
// tile 128x64, 256 threads (4 waves 2x2), K-step 32, no K bounds (zero-padded).
// flags: 1 relu, 2 accumulate fp32 C, 4 QKV-packed-f16 epilogue, 8 bf16 out
__global__ __launch_bounds__(256)
void gemm_mfma(const unsigned short* __restrict__ A,
               const unsigned short* __restrict__ Bt,
               const float* __restrict__ bias,
               float* __restrict__ C, unsigned short* __restrict__ Cbf,
               _Float16* __restrict__ qp, _Float16* __restrict__ kp,
               _Float16* __restrict__ vp,
               int M, int N, int Kpad, int Cstride, int flags)
{
    __shared__ unsigned short As[128 * 40];   // [m][k], stride 40 (pad 8)
    __shared__ unsigned short Bs[64 * 40];    // [n][k], stride 40
    const int tid = threadIdx.x;
    const int bm = blockIdx.x * 128;
    const int bn = blockIdx.y * 64;
    const int wave = tid >> 6, lane = tid & 63;
    const int wm = (wave & 1) * 64, wn = (wave >> 1) * 32;
    const int lq = lane >> 4, lr = lane & 15;
    f32x4 acc[4][2];
    #pragma unroll
    for (int i = 0; i < 4; i++)
        #pragma unroll
        for (int j = 0; j < 2; j++) acc[i][j] = (f32x4){0.f, 0.f, 0.f, 0.f};

    const int ar = tid >> 1;            // A row 0..127
    const int ac = (tid & 1) << 4;      // col base 0/16
    const int brow = tid >> 2;          // B n-row 0..63
    const int bcol = (tid & 3) << 3;    // k base 0,8,16,24
    const unsigned short* asrc = A + (size_t)(bm + ar) * Kpad + ac;
    const bool aok = (bm + ar) < M;
    const unsigned short* bsrc = Bt + (size_t)(bn + brow) * Kpad + bcol;
    const bool bok = (bn + brow) < N;

    const int nkt = Kpad >> 5;
    for (int kt = 0; kt < nkt; kt++) {
        const int k0 = kt << 5;
        uint4 a0 = {0u,0u,0u,0u}, a1 = {0u,0u,0u,0u};
        if (aok) {
            a0 = *(const uint4*)(asrc + k0);
            a1 = *(const uint4*)(asrc + k0 + 8);
        }
        *(uint4*)&As[ar * 40 + ac] = a0;
        *(uint4*)&As[ar * 40 + ac + 8] = a1;
        uint4 bv = {0u,0u,0u,0u};
        if (bok) bv = *(const uint4*)(bsrc + k0);
        *(uint4*)&Bs[brow * 40 + bcol] = bv;
        __syncthreads();
        bf16x8 af[4], bfr[2];
        #pragma unroll
        for (int i = 0; i < 4; i++)
            af[i] = *(const bf16x8*)&As[(wm + i * 16 + lr) * 40 + lq * 8];
        #pragma unroll
        for (int j = 0; j < 2; j++)
            bfr[j] = *(const bf16x8*)&Bs[(wn + j * 16 + lr) * 40 + lq * 8];
        #pragma unroll
        for (int i = 0; i < 4; i++)
            #pragma unroll
            for (int j = 0; j < 2; j++)
                acc[i][j] = __builtin_amdgcn_mfma_f32_16x16x32_bf16(af[i], bfr[j], acc[i][j], 0, 0, 0);
        __syncthreads();
    }

    if (flags & 4) {                       // QKV packed-f16 epilogue (N=720)
        #pragma unroll
        for (int j = 0; j < 2; j++) {
            int n = bn + wn + j * 16 + lr;
            if (n >= N) continue;
            int which = n / 240;
            int rem = n - which * 240;
            int hh = rem / 15;
            int c = rem - hh * 15;
            _Float16* dst = (which == 0) ? qp : (which == 1) ? kp : vp;
            float bias_n = bias[n];
            float mult = (which == 0) ? (SCALE_ * LOG2E_) : 1.f;
            #pragma unroll
            for (int i = 0; i < 4; i++)
                #pragma unroll
                for (int r = 0; r < 4; r++) {
                    int m = bm + wm + i * 16 + lq * 4 + r;
                    if (m >= M) continue;
                    float s = (acc[i][j][r] + bias_n) * mult;
                    int b = m / LP_, l = m - b * LP_;
                    dst[(((size_t)b * H_ + hh) * LP_ + l) * 16 + c] = (_Float16)s;
                }
        }
    } else if (flags & 8) {                // bf16 output
        #pragma unroll
        for (int i = 0; i < 4; i++)
            #pragma unroll
            for (int j = 0; j < 2; j++) {
                int n = bn + wn + j * 16 + lr;
                if (n >= N) continue;
                float bias_n = bias ? bias[n] : 0.f;
                #pragma unroll
                for (int r = 0; r < 4; r++) {
                    int m = bm + wm + i * 16 + lq * 4 + r;
                    if (m >= M) continue;
                    float s = acc[i][j][r] + bias_n;
                    if (flags & 1) s = fmaxf(s, 0.f);
                    Cbf[(size_t)m * Cstride + n] = f2bf(s);
                }
            }
    } else {                               // fp32 output (optionally accumulate)
        #pragma unroll
        for (int i = 0; i < 4; i++)
            #pragma unroll
            for (int j = 0; j < 2; j++) {
                int n = bn + wn + j * 16 + lr;
                if (n >= N) continue;
                float bias_n = bias ? bias[n] : 0.f;
                #pragma unroll
                for (int r = 0; r < 4; r++) {
                    int m = bm + wm + i * 16 + lq * 4 + r;
                    if (m >= M) continue;
                    float s = acc[i][j][r] + bias_n;
                    if (flags & 1) s = fmaxf(s, 0.f);
                    size_t off = (size_t)m * Cstride + n;
                    if (flags & 2) C[off] += s; else C[off] = s;
                }
            }
    }
}

// ------------- LN240: wave-per-row, fp32 in -> bf16 out [rows][256] ----------
__global__ __launch_bounds__(256)
void ln240(const float* __restrict__ in, unsigned short* __restrict__ out,
           const float* __restrict__ g, const float* __restrict__ bb) {
    const int row = blockIdx.x * 4 + (threadIdx.x >> 6);
    const int lane = threadIdx.x & 63;
    const float* x = in + (size_t)row * 240;
    float4 v = {0.f, 0.f, 0.f, 0.f};
    if (lane < 60) v = *(const float4*)(x + lane * 4);
    float s = (v.x + v.y) + (v.z + v.w);
    #pragma unroll
    for (int off = 32; off; off >>= 1) s += __shfl_xor(s, off);
    const float mean = s * (1.f / 240.f);
    float4 d;
    d.x = v.x - mean; d.y = v.y - mean; d.z = v.z - mean; d.w = v.w - mean;
    float vs = (lane < 60) ? (d.x * d.x + d.y * d.y) + (d.z * d.z + d.w * d.w) : 0.f;
    #pragma unroll
    for (int off = 32; off; off >>= 1) vs += __shfl_xor(vs, off);
    const float rs = rsqrtf(vs * (1.f / 240.f) + 1e-5f);
    ushort4 o4 = {0, 0, 0, 0};
    if (lane < 60) {
        float4 g4 = *(const float4*)(g + lane * 4);
        float4 b4 = *(const float4*)(bb + lane * 4);
        o4.x = f2bf(d.x * rs * g4.x + b4.x);
        o4.y = f2bf(d.y * rs * g4.y + b4.y);
        o4.z = f2bf(d.z * rs * g4.z + b4.z);
        o4.w = f2bf(d.w * rs * g4.w + b4.w);
    }
    *(ushort4*)(out + (size_t)row * 256 + lane * 4) = o4;   // lanes 60..63: pad zeros
}

// ------------- LN480+relu: wave-per-row, fp32 in -> bf16 out [rows][480] -----
__global__ __launch_bounds__(256)
void ln480(const float* __restrict__ in, unsigned short* __restrict__ out,
           const float* __restrict__ g, const float* __restrict__ bb) {
    const int row = blockIdx.x * 4 + (threadIdx.x >> 6);
    const int lane = threadIdx.x & 63;
    const float* x = in + (size_t)row * 480;
    float4 va = {0.f,0.f,0.f,0.f}, vb = {0.f,0.f,0.f,0.f};
    if (lane < 60) {
        va = *(const float4*)(x + lane * 8);
        vb = *(const float4*)(x + lane * 8 + 4);
    }
    float s = ((va.x + va.y) + (va.z + va.w)) + ((vb.x + vb.y) + (vb.z + vb.w));
    #pragma unroll
    for (int off = 32; off; off >>= 1) s += __shfl_xor(s, off);
    const float mean = s * (1.f / 480.f);
    float4 da, db;
    da.x = va.x - mean; da.y = va.y - mean; da.z = va.z - mean; da.w = va.w - mean;
    db.x = vb.x - mean; db.y = vb.y - mean; db.z = vb.z - mean; db.w = vb.w - mean;
    float vs = (lane < 60) ? ((da.x*da.x + da.y*da.y) + (da.z*da.z + da.w*da.w)) +
                             ((db.x*db.x + db.y*db.y) + (db.z*db.z + db.w*db.w)) : 0.f;
    #pragma unroll
    for (int off = 32; off; off >>= 1) vs += __shfl_xor(vs, off);
    const float rs = rsqrtf(vs * (1.f / 480.f) + 1e-5f);
    if (lane < 60) {
        float4 ga = *(const float4*)(g + lane * 8);
        float4 gb = *(const float4*)(g + lane * 8 + 4);
        float4 ba = *(const float4*)(bb + lane * 8);
        float4 b2 = *(const float4*)(bb + lane * 8 + 4);
        ushort4 oa, ob;
        oa.x = f2bf(fmaxf(da.x * rs * ga.x + ba.x, 0.f));
        oa.y = f2bf(fmaxf(da.y * rs * ga.y + ba.y, 0.f));
        oa.z = f2bf(fmaxf(da.z * rs * ga.z + ba.z, 0.f));
        oa.w = f2bf(fmaxf(da.w * rs * ga.w + ba.w, 0.f));
        ob.x = f2bf(fmaxf(db.x * rs * gb.x + b2.x, 0.f));
        ob.y = f2bf(fmaxf(db.y * rs * gb.y + b2.y, 0.f));
        ob.z = f2bf(fmaxf(db.z * rs * gb.z + b2.z, 0.f));
        ob.w = f2bf(fmaxf(db.w * rs * gb.w + b2.w, 0.f));
        *(ushort4*)(out + (size_t)row * 480 + lane * 8) = oa;
        *(ushort4*)(out + (size_t)row * 480 + lane * 8 + 4) = ob;
    }
}

// -------- embed finish: LN(g2)+relu+pos for tokens, cls row for l==0 ---------
__global__ void embed_finish(const float* __restrict__ tmp,
                             const float* __restrict__ g, const float* __restrict__ bb,
                             const float* __restrict__ pos, const float* __restrict__ cls,
                             float* __restrict__ h) {
    int row = blockIdx.x;
    int b = row / LP_, l = row % LP_;
    int t = threadIdx.x;
    float* out = h + (size_t)row * D_;
    if (l == 0) {
        if (t < D_) out[t] = cls[t];
        return;
    }
    const float* x = tmp + ((size_t)b * L_ + (l - 1)) * D_;
    float v0 = (t < D_) ? x[t] : 0.f;
    __shared__ float red[256];
    red[t] = v0;
    __syncthreads();
    for (int off = 128; off > 0; off >>= 1) {
        if (t < off) red[t] += red[t + off];
        __syncthreads();
    }
    float mean = red[0] / D_;
    __syncthreads();
    float d0 = (t < D_) ? v0 - mean : 0.f;
    red[t] = d0 * d0;
    __syncthreads();
    for (int off = 128; off > 0; off >>= 1) {
        if (t < off) red[t] += red[t + off];
        __syncthreads();
    }
    float rs = rsqrtf(red[0] / D_ + 1e-5f);
    if (t < D_) {
        float r = d0 * rs * g[t] + bb[t];
        out[t] = fmaxf(r, 0.f) + pos[(size_t)(l - 1) * D_ + t];
    }
}

// ---------------- attention: block per (b,h), 320 thr, thread-per-query ------
// K/V f16 in LDS (uint4 broadcast reads); 4 keys/iter, 8 indep fdot2 chains.
// mask folded into k[15]*q[15]; q pre-scaled by SCALE*log2e. Writes bf16 o.
__global__ __launch_bounds__(320)
void attn_kernel(const _Float16* __restrict__ qp, const _Float16* __restrict__ kp,
                 const _Float16* __restrict__ vp, unsigned short* __restrict__ o)
{
    const int hh = blockIdx.x, b = blockIdx.y;
    const int tid = threadIdx.x;
    __shared__ unsigned int Ks[LP_ * 8];
    __shared__ unsigned int Vs[LP_ * 8];
    const size_t base = ((size_t)b * H_ + hh) * LP_ * 16;
    const uint4* ksrc = (const uint4*)(kp + base);
    const uint4* vsrc = (const uint4*)(vp + base);
    for (int i = tid; i < LP_ * 2; i += 320) {
        ((uint4*)Ks)[i] = ksrc[i];
        ((uint4*)Vs)[i] = vsrc[i];
    }
    __syncthreads();
    const int qi = tid;
    if (qi >= LP_) return;
    const uint4* qsrc = (const uint4*)(qp + base + (size_t)qi * 16);
    const uint4 q0 = qsrc[0], q1 = qsrc[1];
    float l = 0.f;
    float acc[16];
    #pragma unroll
    for (int j = 0; j < 16; j++) acc[j] = 0.f;
    int kk = 0;
    for (; kk + 4 <= LP_; kk += 4) {
        float p[4];
        #pragma unroll
        for (int t = 0; t < 4; t++) {
            const uint4 k0 = *(const uint4*)&Ks[(kk + t) * 8];
            const uint4 k1 = *(const uint4*)&Ks[(kk + t) * 8 + 4];
            float sa = 0.f, sb = 0.f;
            sa = fdot2u(q0.x, k0.x, sa); sb = fdot2u(q0.y, k0.y, sb);
            sa = fdot2u(q0.z, k0.z, sa); sb = fdot2u(q0.w, k0.w, sb);
            sa = fdot2u(q1.x, k1.x, sa); sb = fdot2u(q1.y, k1.y, sb);
            sa = fdot2u(q1.z, k1.z, sa); sb = fdot2u(q1.w, k1.w, sb);
            p[t] = exp2f(sa + sb);
        }
        l += (p[0] + p[1]) + (p[2] + p[3]);
        #pragma unroll
        for (int t = 0; t < 4; t++) {
            const uint4 v0 = *(const uint4*)&Vs[(kk + t) * 8];
            const uint4 v1 = *(const uint4*)&Vs[(kk + t) * 8 + 4];
            const float pt = p[t];
            acc[0]  += pt * h2lo(v0.x);  acc[1]  += pt * h2hi(v0.x);
            acc[2]  += pt * h2lo(v0.y);  acc[3]  += pt * h2hi(v0.y);
            acc[4]  += pt * h2lo(v0.z);  acc[5]  += pt * h2hi(v0.z);
            acc[6]  += pt * h2lo(v0.w);  acc[7]  += pt * h2hi(v0.w);
            acc[8]  += pt * h2lo(v1.x);  acc[9]  += pt * h2hi(v1.x);
            acc[10] += pt * h2lo(v1.y);  acc[11] += pt * h2hi(v1.y);
            acc[12] += pt * h2lo(v1.z);  acc[13] += pt * h2hi(v1.z);
            acc[14] += pt * h2lo(v1.w);  acc[15] += pt * h2hi(v1.w);
        }
    }
    for (; kk < LP_; kk++) {
        const uint4 k0 = *(const uint4*)&Ks[kk * 8];
        const uint4 k1 = *(const uint4*)&Ks[kk * 8 + 4];
        float sa = 0.f, sb = 0.f;
        sa = fdot2u(q0.x, k0.x, sa); sb = fdot2u(q0.y, k0.y, sb);
        sa = fdot2u(q0.z, k0.z, sa); sb = fdot2u(q0.w, k0.w, sb);
        sa = fdot2u(q1.x, k1.x, sa); sb = fdot2u(q1.y, k1.y, sb);
        sa = fdot2u(q1.z, k1.z, sa); sb = fdot2u(q1.w, k1.w, sb);
        float pt = exp2f(sa + sb);
        l += pt;
        const uint4 v0 = *(const uint4*)&Vs[kk * 8];
        const uint4 v1 = *(const uint4*)&Vs[kk * 8 + 4];
        acc[0]  += pt * h2lo(v0.x);  acc[1]  += pt * h2hi(v0.x);
        acc[2]  += pt * h2lo(v0.y);  acc[3]  += pt * h2hi(v0.y);
        acc[4]  += pt * h2lo(v0.z);  acc[5]  += pt * h2hi(v0.z);
        acc[6]  += pt * h2lo(v0.w);  acc[7]  += pt * h2hi(v0.w);
        acc[8]  += pt * h2lo(v1.x);  acc[9]  += pt * h2hi(v1.x);
        acc[10] += pt * h2lo(v1.z);  acc[11] += pt * h2hi(v1.y);
        acc[12] += pt * h2lo(v1.z);  acc[13] += pt * h2hi(v1.z);
        acc[14] += pt * h2lo(v1.w);  acc[15] += pt * h2hi(v1.w);
    }
    const float inv = 1.f / l;
    unsigned short* orow = o + (size_t)(b * LP_ + qi) * 256 + hh * DK_;
    #pragma unroll
    for (int j = 0; j < DK_; j++) orow[j] = f2bf(acc[j] * inv);
    if (hh == 0) {
        unsigned short* pr = o + (size_t)(b * LP_ + qi) * 256 + 240;
        #pragma unroll
        for (int j = 0; j < 16; j++) pr[j] = 0;
    }
}

// ---------------- masked mean pool -------------------------------------------
__global__ void pool_kernel(const float* __restrict__ h, const float* __restrict__ mask,
                            float* __restrict__ pool) {
    int b = blockIdx.x;
    int d = threadIdx.x;
    if (d >= D_) return;
    float s = 0.f, c = 0.f;
    for (int l = 0; l < LP_; l++) {
        if (mask[b * LP_ + l] == 0.f) {
            s += h[((size_t)b * LP_ + l) * D_ + d];
            c += 1.f;
        }
    }
    pool[b * D_ + d] = s / c;
}

// ---------------- logits -----------------------------------------------------
__global__ void logits_kernel(const float* __restrict__ pool, const float* __restrict__ W,
                              const float* __restrict__ bias, float* __restrict__ out) {
    int idx = blockIdx.x * blockDim.x + threadIdx.x;
    if (idx >= B_ * NC_) return;
    int b = idx / NC_, n = idx - b * NC_;
    float s = bias[n];
    const float* p = pool + b * D_;
    for (int kk = 0; kk < D_; kk++) s += p[kk] * W[(size_t)kk * NC_ + n];
    out[idx] = s;
}

extern "C" void kernel_launch(void* const* d_in, const int* in_sizes, int n_in,
                              void* d_out, int out_size, void* d_ws, size_t ws_size,
                              hipStream_t stream) {
    const float* x        = (const float*)d_in[0];
    const float* pos      = (const float*)d_in[1];
    const float* cls      = (const float*)d_in[2];
    const float* e_W1     = (const float*)d_in[3];
    const float* e_b1     = (const float*)d_in[4];
    const float* e_g1     = (const float*)d_in[5];
    const float* e_bn1    = (const float*)d_in[6];
    const float* e_W2     = (const float*)d_in[7];
    const float* e_b2     = (const float*)d_in[8];
    const float* e_g2     = (const float*)d_in[9];
    const float* e_bn2    = (const float*)d_in[10];
    const float* ln1_g    = (const float*)d_in[11];
    const float* ln1_b    = (const float*)d_in[12];
    const float* Wq       = (const float*)d_in[13];
    const float* bq       = (const float*)d_in[14];
    const float* Wk       = (const float*)d_in[15];
    const float* bk       = (const float*)d_in[16];
    const float* Wv       = (const float*)d_in[17];
    const float* bv       = (const float*)d_in[18];
    const float* Wo       = (const float*)d_in[19];
    const float* bo       = (const float*)d_in[20];
    const float* ln2_g    = (const float*)d_in[21];
    const float* ln2_b    = (const float*)d_in[22];
    const float* W1       = (const float*)d_in[23];
    const float* b1       = (const float*)d_in[24];
    const float* W2       = (const float*)d_in[25];
    const float* b2       = (const float*)d_in[26];
    const float* logit_W  = (const float*)d_in[27];
    const float* logit_b  = (const float*)d_in[28];
    float* out = (float*)d_out;

    const size_t TOK = (size_t)B_ * LP_;       // 8224
    const size_t HN  = TOK * D_;               // 1,973,760
    const size_t QN  = (size_t)B_ * H_ * LP_ * 16;  // 2,105,344

    // ---- workspace layout (bytes, 16B aligned) ----
    char* wsb = (char*)d_ws;
    size_t cur = 0;
    auto take = [&](size_t bytes) { void* p = wsb + cur; cur += (bytes + 15) & ~15ULL; return p; };
    float* mask = (float*)take(8224 * 4);
    float* h    = (float*)take(HN * 4);
    float* b720 = (float*)take(NB_ * 720 * 4);
    float* pl   = (float*)take(B_ * D_ * 4);
    // region A: embed gemm1 fp32 out [8192][480]  <->  FFN hidden bf16 [8224][480]
    void* regionA = take((size_t)8192 * 480 * 4);
    float* tmp1 = (float*)regionA;
    unsigned short* tbf = (unsigned short*)regionA;
    // region B: embed gemm2 fp32 out [8192][240] <-> ybf[8224][256]+obf[8224][256]
    void* regionB = take(TOK * 256 * 2 * 2);
    float* y32 = (float*)regionB;
    unsigned short* ybf = (unsigned short*)regionB;
    unsigned short* obf = ybf + TOK * 256;
    unsigned short* xbf  = (unsigned short*)take((size_t)8192 * 192 * 2);
    unsigned short* We1  = (unsigned short*)take((size_t)480 * 192 * 2);
    unsigned short* We2  = (unsigned short*)take((size_t)240 * 480 * 2);
    unsigned short* Wqkv = (unsigned short*)take((size_t)NB_ * 720 * 256 * 2);
    unsigned short* WoT  = (unsigned short*)take((size_t)NB_ * 240 * 256 * 2);
    unsigned short* W1T  = (unsigned short*)take((size_t)NB_ * 480 * 256 * 2);
    unsigned short* W2T  = (unsigned short*)take((size_t)NB_ * 240 * 480 * 2);
    // qkv packed region; embed LN1 bf16 out [8192][480] aliases qp+kp (dead before attn_init)
    _Float16* qp = (_Float16*)take(QN * 3 * 2);
    _Float16* kp = qp + QN;
    _Float16* vp = kp + QN;
    unsigned short* t480bf = (unsigned short*)qp;

    const int BS = 256;
    auto blocks = [](size_t n) { return (int)((n + 255) / 256); };

    // prep
    mask_kernel<<<blocks(TOK), BS, 0, stream>>>(x, mask);
    pack_bias<<<NB_, BS, 0, stream>>>(bq, bk, bv, b720);
    cvt_x<<<8192, 64, 0, stream>>>(x, xbf);
    pretrans<<<dim3(480, 1), 64, 0, stream>>>(e_W1, We1, PD_, 480, 192, 0, 0);
    pretrans<<<dim3(240, 1), 64, 0, stream>>>(e_W2, We2, 480, 240, 480, 0, 0);
    pretrans<<<dim3(240, NB_), 64, 0, stream>>>(Wq, Wqkv,           240, 240, 256, 240*240, 720*256);
    pretrans<<<dim3(240, NB_), 64, 0, stream>>>(Wk, Wqkv + 240*256, 240, 240, 256, 240*240, 720*256);
    pretrans<<<dim3(240, NB_), 64, 0, stream>>>(Wv, Wqkv + 480*256, 240, 240, 256, 240*240, 720*256);
    pretrans<<<dim3(240, NB_), 64, 0, stream>>>(Wo, WoT,            240, 240, 256, 240*240, 240*256);
    pretrans<<<dim3(480, NB_), 64, 0, stream>>>(W1, W1T,            240, 480, 256, 240*480, 480*256);
    pretrans<<<dim3(240, NB_), 64, 0, stream>>>(W2, W2T,            480, 240, 480, 480*240, 240*480);

    // embed
    gemm_mfma<<<dim3(64, 8), BS, 0, stream>>>(xbf, We1, e_b1, tmp1, nullptr,
                                              nullptr, nullptr, nullptr,
                                              8192, 480, 192, 480, 0);
    ln480<<<2048, BS, 0, stream>>>(tmp1, t480bf, e_g1, e_bn1);
    gemm_mfma<<<dim3(64, 4), BS, 0, stream>>>(t480bf, We2, e_b2, y32, nullptr,
                                              nullptr, nullptr, nullptr,
                                              8192, 240, 480, 240, 0);
    embed_finish<<<(int)TOK, BS, 0, stream>>>(y32, e_g2, e_bn2, pos, cls, h);
    attn_init<<<blocks((size_t)B_ * H_ * LP_), BS, 0, stream>>>(mask, qp, kp, vp);

    for (int i = 0; i < NB_; i++) {
        ln240<<<(int)(TOK / 4), BS, 0, stream>>>(h, ybf, ln1_g + i * D_, ln1_b + i * D_);
        gemm_mfma<<<dim3(65, 12), BS, 0, stream>>>(ybf, Wqkv + (size_t)i * 720 * 256,
                                                   b720 + i * 720, nullptr, nullptr,
                                                   qp, kp, vp,
                                                   (int)TOK, 720, 256, 0, 4);
        attn_kernel<<<dim3(H_, B_), 320, 0, stream>>>(qp, kp, vp, obf);
        gemm_mfma<<<dim3(65, 4), BS, 0, stream>>>(obf, WoT + (size_t)i * 240 * 256,
                                                  bo + i * D_, h, nullptr,
                                                  nullptr, nullptr, nullptr,
                                                  (int)TOK, 240, 256, 240, 2);
        ln240<<<(int)(TOK / 4), BS, 0, stream>>>(h, ybf, ln2_g + i * D_, ln2_b + i * D_);
        gemm_mfma<<<dim3(65, 8), BS, 0, stream>>>(ybf, W1T + (size_t)i * 480 * 256,
                                                  b1 + i * HID_, nullptr, tbf,
                                                  nullptr, nullptr, nullptr,
                                                  (int)TOK, 480, 256, 480, 1 | 8);
        gemm_mfma<<<dim3(65, 4), BS, 0, stream>>>(tbf, W2T + (size_t)i * 240 * 480,
                                                  b2 + i * D_, h, nullptr,
                                                  nullptr, nullptr, nullptr,
                                                  (int)TOK, 240, 480, 240, 2);
    }

    pool_kernel<<<B_, BS, 0, stream>>>(h, mask, pl);
    logits_kernel<<<blocks((size_t)B_ * NC_), BS, 0, stream>>>(pl, logit_W, logit_b, out);
}

// Round 5
// 1178.190 us; speedup vs baseline: 7.2135x; 1.1681x over previous
//
#include <hip/hip_runtime.h>
#include <math.h>

#define B_  32
#define L_  256
#define PD_ 164
#define D_  240
#define H_  16
#define NB_ 6
#define NC_ 250
#define DK_ 15
#define HID_ 480
#define LP_ 257
#define SCALE_ 0.2581988897471611f   // 1/sqrt(15)
#define LOG2E_ 1.4426950408889634f

typedef __attribute__((ext_vector_type(8))) short bf16x8;
typedef __attribute__((ext_vector_type(4))) float f32x4;
typedef _Float16 h2 __attribute__((ext_vector_type(2)));

static __device__ inline unsigned short f2bf(float x) {
    unsigned u = __builtin_bit_cast(unsigned, x);
    u += 0x7FFFu + ((u >> 16) & 1u);     // RNE (finite values only)
    return (unsigned short)(u >> 16);
}
static __device__ inline float fdot2u(unsigned a, unsigned b, float c) {
    return __builtin_amdgcn_fdot2(__builtin_bit_cast(h2, a),
                                  __builtin_bit_cast(h2, b), c, false);
}
static __device__ inline float h2lo(unsigned u) { h2 v = __builtin_bit_cast(h2, u); return (float)v.x; }
static __device__ inline float h2hi(unsigned u) { h2 v = __builtin_bit_cast(h2, u); return (float)v.y; }

// async global->LDS, 16B per lane; lds dest must be wave-uniform base (+lane*16)
static __device__ inline void gl2lds16(const void* g, void* l) {
    __builtin_amdgcn_global_load_lds(
        (const __attribute__((address_space(1))) unsigned int*)g,
        (__attribute__((address_space(3))) unsigned int*)l, 16, 0, 0);
}

// ---------------- mask ----------------
__global__ void mask_kernel(const float* __restrict__ x, float* __restrict__ mask) {
    int idx = blockIdx.x * blockDim.x + threadIdx.x;
    if (idx >= B_ * LP_) return;
    int b = idx / LP_, l = idx % LP_;
    if (l == 0) { mask[idx] = 0.f; return; }
    const float* xr = x + ((size_t)b * L_ + (l - 1)) * PD_;
    float mx = -1e30f;
    for (int j = 0; j < PD_; j++) mx = fmaxf(mx, xr[j]);
    mask[idx] = (mx == 0.f) ? 1.f : 0.f;
}

// --------- x fp32 [8192][164] -> bf16 [8192][192] (zero pad) -----------------
__global__ void cvt_x(const float* __restrict__ x, unsigned short* __restrict__ xbf) {
    int row = blockIdx.x;
    const float* src = x + (size_t)row * PD_;
    unsigned short* dst = xbf + (size_t)row * 192;
    for (int k = threadIdx.x; k < 192; k += 64)
        dst[k] = f2bf(k < PD_ ? src[k] : 0.f);
}

// --------- weight pretranspose: fp32 [batch][K][N] -> bf16 [batch][N][Kpad] --
__global__ void pretrans(const float* __restrict__ W, unsigned short* __restrict__ out,
                         int K, int N, int Kpad, long sstride, long dstride) {
    int n = blockIdx.x, bb = blockIdx.y;
    const float* src = W + (size_t)bb * sstride;
    unsigned short* dst = out + (size_t)bb * dstride + (size_t)n * Kpad;
    for (int k = threadIdx.x; k < Kpad; k += 64)
        dst[k] = f2bf((k < K && n < N) ? src[(size_t)k * N + n] : 0.f);
}

// --------- init c==15 lanes of packed q/k/v (mask folding) -------------------
__global__ void attn_init(const float* __restrict__ mask, _Float16* __restrict__ qp,
                          _Float16* __restrict__ kp, _Float16* __restrict__ vp) {
    int idx = blockIdx.x * blockDim.x + threadIdx.x;   // (b*H+h)*LP + l
    if (idx >= B_ * H_ * LP_) return;
    int l = idx % LP_;
    int b = idx / (H_ * LP_);
    qp[(size_t)idx * 16 + 15] = (_Float16)LOG2E_;
    kp[(size_t)idx * 16 + 15] = (_Float16)((mask[b * LP_ + l] != 0.f) ? -10000.f : 0.f);
    vp[(size_t)idx * 16 + 15] = (_Float16)0.f;
}

// --------- pack bq|bk|bv per layer into one 720-vector -----------------------
__global__ void pack_bias(const float* __restrict__ bq, const float* __restrict__ bk,
                          const float* __restrict__ bv, float* __restrict__ b720) {
    int i = blockIdx.x;
    for (int n = threadIdx.x; n < 720; n += 256) {
        float v = (n < 240) ? bq[i * 240 + n]
                : (n < 480) ? bk[i * 240 + n - 240]
                            : bv[i * 240 + n - 480];
        b720[i * 720 + n] = v;
    }
}

// ---------------- MFMA GEMM: C = A[M,Kpad]bf16 @ Bt[N,Kpad]bf16 --------------
// tile 128x64, 4 waves (2x2), K-step 32. Staging via global_load_lds (16B/lane)
// into load-order-contiguous LDS ([row][32] ushort, no pad). A/B allocations
// are row-padded to tile multiples (OOB rows feed only discarded C rows).
// flags: 1 relu, 2 accumulate fp32 C, 4 QKV-packed-f16 epilogue, 8 bf16 out
__global__ __launch_bounds__(256)
void gemm_mfma(const unsigned short* __restrict__ A,
               const unsigned short* __restrict__ Bt,
               const float* __restrict__ bias,
               float* __restrict__ C, unsigned short* __restrict__ Cbf,
               _Float16* __restrict__ qp, _Float16* __restrict__ kp,
               _Float16* __restrict__ vp,
               int M, int N, int Kpad, int Cstride, int flags)
{
    __shared__ __align__(16) unsigned short As[128 * 32];   // 8 KB
    __shared__ __align__(16) unsigned short Bs[64 * 32];    // 4 KB
    const int tid = threadIdx.x;
    const int bm = blockIdx.x * 128;
    const int bn = blockIdx.y * 64;
    const int wave = tid >> 6, lane = tid & 63;
    const int wm = (wave & 1) * 64, wn = (wave >> 1) * 32;
    const int lq = lane >> 4, lr = lane & 15;

    f32x4 acc[4][2];
    #pragma unroll
    for (int i = 0; i < 4; i++)
        #pragma unroll
        for (int j = 0; j < 2; j++) acc[i][j] = (f32x4){0.f, 0.f, 0.f, 0.f};

    // staging addresses: each wave stages A rows [wave*32, wave*32+32) (2 instrs)
    // and B rows [wave*16, wave*16+16) (1 instr); lane = row*4 + chunk(8 ushort)
    const int srow = lane >> 2;            // 0..15
    const int schk = (lane & 3) << 3;      // 0,8,16,24
    const unsigned short* ga0 = A + (size_t)(bm + wave * 32 + srow) * Kpad + schk;
    const unsigned short* ga1 = A + (size_t)(bm + wave * 32 + 16 + srow) * Kpad + schk;
    const unsigned short* gb  = Bt + (size_t)(bn + wave * 16 + srow) * Kpad + schk;
    char* la0 = (char*)As + wave * 2048;
    char* la1 = (char*)As + wave * 2048 + 1024;
    char* lb  = (char*)Bs + wave * 1024;

    const int nkt = Kpad >> 5;
    for (int kt = 0; kt < nkt; kt++) {
        gl2lds16(ga0, la0);
        gl2lds16(ga1, la1);
        gl2lds16(gb, lb);
        ga0 += 32; ga1 += 32; gb += 32;
        __syncthreads();
        bf16x8 af[4], bfr[2];
        #pragma unroll
        for (int i = 0; i < 4; i++)
            af[i] = *(const bf16x8*)&As[(wm + i * 16 + lr) * 32 + lq * 8];
        #pragma unroll
        for (int j = 0; j < 2; j++)
            bfr[j] = *(const bf16x8*)&Bs[(wn + j * 16 + lr) * 32 + lq * 8];
        #pragma unroll
        for (int i = 0; i < 4; i++)
            #pragma unroll
            for (int j = 0; j < 2; j++)
                acc[i][j] = __builtin_amdgcn_mfma_f32_16x16x32_bf16(af[i], bfr[j], acc[i][j], 0, 0, 0);
        __syncthreads();
    }

    if (flags & 4) {                       // QKV packed-f16 epilogue (N=720)
        #pragma unroll
        for (int j = 0; j < 2; j++) {
            int n = bn + wn + j * 16 + lr;
            if (n >= N) continue;
            int which = n / 240;
            int rem = n - which * 240;
            int hh = rem / 15;
            int c = rem - hh * 15;
            _Float16* dst = (which == 0) ? qp : (which == 1) ? kp : vp;
            float bias_n = bias[n];
            float mult = (which == 0) ? (SCALE_ * LOG2E_) : 1.f;
            #pragma unroll
            for (int i = 0; i < 4; i++)
                #pragma unroll
                for (int r = 0; r < 4; r++) {
                    int m = bm + wm + i * 16 + lq * 4 + r;
                    if (m >= M) continue;
                    float s = (acc[i][j][r] + bias_n) * mult;
                    int b = m / LP_, l = m - b * LP_;
                    dst[(((size_t)b * H_ + hh) * LP_ + l) * 16 + c] = (_Float16)s;
                }
        }
    } else if (flags & 8) {                // bf16 output
        #pragma unroll
        for (int i = 0; i < 4; i++)
            #pragma unroll
            for (int j = 0; j < 2; j++) {
                int n = bn + wn + j * 16 + lr;
                if (n >= N) continue;
                float bias_n = bias ? bias[n] : 0.f;
                #pragma unroll
                for (int r = 0; r < 4; r++) {
                    int m = bm + wm + i * 16 + lq * 4 + r;
                    if (m >= M) continue;
                    float s = acc[i][j][r] + bias_n;
                    if (flags & 1) s = fmaxf(s, 0.f);
                    Cbf[(size_t)m * Cstride + n] = f2bf(s);
                }
            }
    } else {                               // fp32 output (optionally accumulate)
        #pragma unroll
        for (int i = 0; i < 4; i++)
            #pragma unroll
            for (int j = 0; j < 2; j++) {
                int n = bn + wn + j * 16 + lr;
                if (n >= N) continue;
                float bias_n = bias ? bias[n] : 0.f;
                #pragma unroll
                for (int r = 0; r < 4; r++) {
                    int m = bm + wm + i * 16 + lq * 4 + r;
                    if (m >= M) continue;
                    float s = acc[i][j][r] + bias_n;
                    if (flags & 1) s = fmaxf(s, 0.f);
                    size_t off = (size_t)m * Cstride + n;
                    if (flags & 2) C[off] += s; else C[off] = s;
                }
            }
    }
}

// ------------- LN240: wave-per-row, fp32 in -> bf16 out [rows][256] ----------
__global__ __launch_bounds__(256)
void ln240(const float* __restrict__ in, unsigned short* __restrict__ out,
           const float* __restrict__ g, const float* __restrict__ bb) {
    const int row = blockIdx.x * 4 + (threadIdx.x >> 6);
    const int lane = threadIdx.x & 63;
    const float* x = in + (size_t)row * 240;
    float4 v = {0.f, 0.f, 0.f, 0.f};
    if (lane < 60) v = *(const float4*)(x + lane * 4);
    float s = (v.x + v.y) + (v.z + v.w);
    #pragma unroll
    for (int off = 32; off; off >>= 1) s += __shfl_xor(s, off);
    const float mean = s * (1.f / 240.f);
    float4 d;
    d.x = v.x - mean; d.y = v.y - mean; d.z = v.z - mean; d.w = v.w - mean;
    float vs = (lane < 60) ? (d.x * d.x + d.y * d.y) + (d.z * d.z + d.w * d.w) : 0.f;
    #pragma unroll
    for (int off = 32; off; off >>= 1) vs += __shfl_xor(vs, off);
    const float rs = rsqrtf(vs * (1.f / 240.f) + 1e-5f);
    ushort4 o4 = {0, 0, 0, 0};
    if (lane < 60) {
        float4 g4 = *(const float4*)(g + lane * 4);
        float4 b4 = *(const float4*)(bb + lane * 4);
        o4.x = f2bf(d.x * rs * g4.x + b4.x);
        o4.y = f2bf(d.y * rs * g4.y + b4.y);
        o4.z = f2bf(d.z * rs * g4.z + b4.z);
        o4.w = f2bf(d.w * rs * g4.w + b4.w);
    }
    *(ushort4*)(out + (size_t)row * 256 + lane * 4) = o4;   // lanes 60..63: pad zeros
}

// ------------- LN480+relu: wave-per-row, fp32 in -> bf16 out [rows][480] -----
__global__ __launch_bounds__(256)
void ln480(const float* __restrict__ in, unsigned short* __restrict__ out,
           const float* __restrict__ g, const float* __restrict__ bb) {
    const int row = blockIdx.x * 4 + (threadIdx.x >> 6);
    const int lane = threadIdx.x & 63;
    const float* x = in + (size_t)row * 480;
    float4 va = {0.f,0.f,0.f,0.f}, vb = {0.f,0.f,0.f,0.f};
    if (lane < 60) {
        va = *(const float4*)(x + lane * 8);
        vb = *(const float4*)(x + lane * 8 + 4);
    }
    float s = ((va.x + va.y) + (va.z + va.w)) + ((vb.x + vb.y) + (vb.z + vb.w));
    #pragma unroll
    for (int off = 32; off; off >>= 1) s += __shfl_xor(s, off);
    const float mean = s * (1.f / 480.f);
    float4 da, db;
    da.x = va.x - mean; da.y = va.y - mean; da.z = va.z - mean; da.w = va.w - mean;
    db.x = vb.x - mean; db.y = vb.y - mean; db.z = vb.z - mean; db.w = vb.w - mean;
    float vs = (lane < 60) ? ((da.x*da.x + da.y*da.y) + (da.z*da.z + da.w*da.w)) +
                             ((db.x*db.x + db.y*db.y) + (db.z*db.z + db.w*db.w)) : 0.f;
    #pragma unroll
    for (int off = 32; off; off >>= 1) vs += __shfl_xor(vs, off);
    const float rs = rsqrtf(vs * (1.f / 480.f) + 1e-5f);
    if (lane < 60) {
        float4 ga = *(const float4*)(g + lane * 8);
        float4 gb = *(const float4*)(g + lane * 8 + 4);
        float4 ba = *(const float4*)(bb + lane * 8);
        float4 b2 = *(const float4*)(bb + lane * 8 + 4);
        ushort4 oa, ob;
        oa.x = f2bf(fmaxf(da.x * rs * ga.x + ba.x, 0.f));
        oa.y = f2bf(fmaxf(da.y * rs * ga.y + ba.y, 0.f));
        oa.z = f2bf(fmaxf(da.z * rs * ga.z + ba.z, 0.f));
        oa.w = f2bf(fmaxf(da.w * rs * ga.w + ba.w, 0.f));
        ob.x = f2bf(fmaxf(db.x * rs * gb.x + b2.x, 0.f));
        ob.y = f2bf(fmaxf(db.y * rs * gb.y + b2.y, 0.f));
        ob.z = f2bf(fmaxf(db.z * rs * gb.z + b2.z, 0.f));
        ob.w = f2bf(fmaxf(db.w * rs * gb.w + b2.w, 0.f));
        *(ushort4*)(out + (size_t)row * 480 + lane * 8) = oa;
        *(ushort4*)(out + (size_t)row * 480 + lane * 8 + 4) = ob;
    }
}

// -------- embed finish: LN(g2)+relu+pos for tokens, cls row for l==0 ---------
__global__ void embed_finish(const float* __restrict__ tmp,
                             const float* __restrict__ g, const float* __restrict__ bb,
                             const float* __restrict__ pos, const float* __restrict__ cls,
                             float* __restrict__ h) {
    int row = blockIdx.x;
    int b = row / LP_, l = row % LP_;
    int t = threadIdx.x;
    float* out = h + (size_t)row * D_;
    if (l == 0) {
        if (t < D_) out[t] = cls[t];
        return;
    }
    const float* x = tmp + ((size_t)b * L_ + (l - 1)) * D_;
    float v0 = (t < D_) ? x[t] : 0.f;
    __shared__ float red[256];
    red[t] = v0;
    __syncthreads();
    for (int off = 128; off > 0; off >>= 1) {
        if (t < off) red[t] += red[t + off];
        __syncthreads();
    }
    float mean = red[0] / D_;
    __syncthreads();
    float d0 = (t < D_) ? v0 - mean : 0.f;
    red[t] = d0 * d0;
    __syncthreads();
    for (int off = 128; off > 0; off >>= 1) {
        if (t < off) red[t] += red[t + off];
        __syncthreads();
    }
    float rs = rsqrtf(red[0] / D_ + 1e-5f);
    if (t < D_) {
        float r = d0 * rs * g[t] + bb[t];
        out[t] = fmaxf(r, 0.f) + pos[(size_t)(l - 1) * D_ + t];
    }
}

// ---------------- attention: block per (b,h), 320 thr, thread-per-query ------
// K f16 + V fp32 in LDS (broadcast reads); 4 keys/iter, 8 indep fdot2 chains.
// mask folded into k[15]*q[15]; q pre-scaled by SCALE*log2e. Writes bf16 o.
__global__ __launch_bounds__(320)
void attn_kernel(const _Float16* __restrict__ qp, const _Float16* __restrict__ kp,
                 const _Float16* __restrict__ vp, unsigned short* __restrict__ o)
{
    const int hh = blockIdx.x, b = blockIdx.y;
    const int tid = threadIdx.x;
    __shared__ unsigned int Ks[LP_ * 8];
    __shared__ float Vs[LP_ * 16];
    const size_t base = ((size_t)b * H_ + hh) * LP_ * 16;
    const uint4* ksrc = (const uint4*)(kp + base);
    const uint4* vsrc = (const uint4*)(vp + base);
    for (int i = tid; i < LP_ * 2; i += 320) {
        ((uint4*)Ks)[i] = ksrc[i];
        uint4 vv = vsrc[i];
        float4 f0 = {h2lo(vv.x), h2hi(vv.x), h2lo(vv.y), h2hi(vv.y)};
        float4 f1 = {h2lo(vv.z), h2hi(vv.z), h2lo(vv.w), h2hi(vv.w)};
        *(float4*)&Vs[i * 8] = f0;
        *(float4*)&Vs[i * 8 + 4] = f1;
    }
    __syncthreads();
    const int qi = tid;
    if (qi >= LP_) return;
    const uint4* qsrc = (const uint4*)(qp + base + (size_t)qi * 16);
    const uint4 q0 = qsrc[0], q1 = qsrc[1];
    float l = 0.f;
    float acc[16];
    #pragma unroll
    for (int j = 0; j < 16; j++) acc[j] = 0.f;
    int kk = 0;
    for (; kk + 4 <= LP_; kk += 4) {
        float p[4];
        #pragma unroll
        for (int t = 0; t < 4; t++) {
            const uint4 k0 = *(const uint4*)&Ks[(kk + t) * 8];
            const uint4 k1 = *(const uint4*)&Ks[(kk + t) * 8 + 4];
            float sa = fdot2u(q0.x, k0.x, 0.f), sb = fdot2u(q0.y, k0.y, 0.f);
            sa = fdot2u(q0.z, k0.z, sa); sb = fdot2u(q0.w, k0.w, sb);
            sa = fdot2u(q1.x, k1.x, sa); sb = fdot2u(q1.y, k1.y, sb);
            sa = fdot2u(q1.z, k1.z, sa); sb = fdot2u(q1.w, k1.w, sb);
            p[t] = exp2f(sa + sb);
        }
        l += (p[0] + p[1]) + (p[2] + p[3]);
        #pragma unroll
        for (int t = 0; t < 4; t++) {
            const float4 va = *(const float4*)&Vs[(kk + t) * 16];
            const float4 vb = *(const float4*)&Vs[(kk + t) * 16 + 4];
            const float4 vc = *(const float4*)&Vs[(kk + t) * 16 + 8];
            const float4 vd = *(const float4*)&Vs[(kk + t) * 16 + 12];
            const float pt = p[t];
            acc[0]  += pt * va.x;  acc[1]  += pt * va.y;
            acc[2]  += pt * va.z;  acc[3]  += pt * va.w;
            acc[4]  += pt * vb.x;  acc[5]  += pt * vb.y;
            acc[6]  += pt * vb.z;  acc[7]  += pt * vb.w;
            acc[8]  += pt * vc.x;  acc[9]  += pt * vc.y;
            acc[10] += pt * vc.z;  acc[11] += pt * vc.w;
            acc[12] += pt * vd.x;  acc[13] += pt * vd.y;
            acc[14] += pt * vd.z;  acc[15] += pt * vd.w;
        }
    }
    for (; kk < LP_; kk++) {
        const uint4 k0 = *(const uint4*)&Ks[kk * 8];
        const uint4 k1 = *(const uint4*)&Ks[kk * 8 + 4];
        float sa = fdot2u(q0.x, k0.x, 0.f), sb = fdot2u(q0.y, k0.y, 0.f);
        sa = fdot2u(q0.z, k0.z, sa); sb = fdot2u(q0.w, k0.w, sb);
        sa = fdot2u(q1.x, k1.x, sa); sb = fdot2u(q1.y, k1.y, sb);
        sa = fdot2u(q1.z, k1.z, sa); sb = fdot2u(q1.w, k1.w, sb);
        float pt = exp2f(sa + sb);
        l += pt;
        const float4 va = *(const float4*)&Vs[kk * 16];
        const float4 vb = *(const float4*)&Vs[kk * 16 + 4];
        const float4 vc = *(const float4*)&Vs[kk * 16 + 8];
        const float4 vd = *(const float4*)&Vs[kk * 16 + 12];
        acc[0]  += pt * va.x;  acc[1]  += pt * va.y;
        acc[2]  += pt * va.z;  acc[3]  += pt * va.w;
        acc[4]  += pt * vb.x;  acc[5]  += pt * vb.y;
        acc[6]  += pt * vb.z;  acc[7]  += pt * vb.w;
        acc[8]  += pt * vc.x;  acc[9]  += pt * vc.y;
        acc[10] += pt * vc.z;  acc[11] += pt * vc.w;
        acc[12] += pt * vd.x;  acc[13] += pt * vd.y;
        acc[14] += pt * vd.z;  acc[15] += pt * vd.w;
    }
    const float inv = 1.f / l;
    unsigned short* orow = o + (size_t)(b * LP_ + qi) * 256 + hh * DK_;
    #pragma unroll
    for (int j = 0; j < DK_; j++) orow[j] = f2bf(acc[j] * inv);
    if (hh == 0) {
        unsigned short* pr = o + (size_t)(b * LP_ + qi) * 256 + 240;
        #pragma unroll
        for (int j = 0; j < 16; j++) pr[j] = 0;
    }
}

// ---------------- masked mean pool -------------------------------------------
__global__ void pool_kernel(const float* __restrict__ h, const float* __restrict__ mask,
                            float* __restrict__ pool) {
    int b = blockIdx.x;
    int d = threadIdx.x;
    if (d >= D_) return;
    float s = 0.f, c = 0.f;
    for (int l = 0; l < LP_; l++) {
        if (mask[b * LP_ + l] == 0.f) {
            s += h[((size_t)b * LP_ + l) * D_ + d];
            c += 1.f;
        }
    }
    pool[b * D_ + d] = s / c;
}

// ---------------- logits -----------------------------------------------------
__global__ void logits_kernel(const float* __restrict__ pool, const float* __restrict__ W,
                              const float* __restrict__ bias, float* __restrict__ out) {
    int idx = blockIdx.x * blockDim.x + threadIdx.x;
    if (idx >= B_ * NC_) return;
    int b = idx / NC_, n = idx - b * NC_;
    float s = bias[n];
    const float* p = pool + b * D_;
    for (int kk = 0; kk < D_; kk++) s += p[kk] * W[(size_t)kk * NC_ + n];
    out[idx] = s;
}

extern "C" void kernel_launch(void* const* d_in, const int* in_sizes, int n_in,
                              void* d_out, int out_size, void* d_ws, size_t ws_size,
                              hipStream_t stream) {
    const float* x        = (const float*)d_in[0];
    const float* pos      = (const float*)d_in[1];
    const float* cls      = (const float*)d_in[2];
    const float* e_W1     = (const float*)d_in[3];
    const float* e_b1     = (const float*)d_in[4];
    const float* e_g1     = (const float*)d_in[5];
    const float* e_bn1    = (const float*)d_in[6];
    const float* e_W2     = (const float*)d_in[7];
    const float* e_b2     = (const float*)d_in[8];
    const float* e_g2     = (const float*)d_in[9];
    const float* e_bn2    = (const float*)d_in[10];
    const float* ln1_g    = (const float*)d_in[11];
    const float* ln1_b    = (const float*)d_in[12];
    const float* Wq       = (const float*)d_in[13];
    const float* bq       = (const float*)d_in[14];
    const float* Wk       = (const float*)d_in[15];
    const float* bk       = (const float*)d_in[16];
    const float* Wv       = (const float*)d_in[17];
    const float* bv       = (const float*)d_in[18];
    const float* Wo       = (const float*)d_in[19];
    const float* bo       = (const float*)d_in[20];
    const float* ln2_g    = (const float*)d_in[21];
    const float* ln2_b    = (const float*)d_in[22];
    const float* W1       = (const float*)d_in[23];
    const float* b1       = (const float*)d_in[24];
    const float* W2       = (const float*)d_in[25];
    const float* b2       = (const float*)d_in[26];
    const float* logit_W  = (const float*)d_in[27];
    const float* logit_b  = (const float*)d_in[28];
    float* out = (float*)d_out;

    const size_t TOK  = (size_t)B_ * LP_;            // 8224
    const size_t TOKP = 8320;                        // padded to 65*128
    const size_t HN   = TOK * D_;
    const size_t QN   = (size_t)B_ * H_ * LP_ * 16;  // 2,105,344

    // ---- workspace layout (bytes, 16B aligned) ----
    char* wsb = (char*)d_ws;
    size_t cur = 0;
    auto take = [&](size_t bytes) { void* p = wsb + cur; cur += (bytes + 15) & ~15ULL; return p; };
    float* mask = (float*)take(8224 * 4);
    float* h    = (float*)take(HN * 4);
    float* b720 = (float*)take(NB_ * 720 * 4);
    float* pl   = (float*)take(B_ * D_ * 4);
    // region A: embed gemm1 fp32 out [8192][480]  <->  FFN hidden bf16 [8320][480]
    void* regionA = take((size_t)8192 * 480 * 4);
    float* tmp1 = (float*)regionA;
    unsigned short* tbf = (unsigned short*)regionA;
    // region B: embed gemm2 fp32 out [8192][240] <-> ybf[8320][256]+obf[8320][256]
    void* regionB = take(TOKP * 256 * 2 * 2);
    float* y32 = (float*)regionB;
    unsigned short* ybf = (unsigned short*)regionB;
    unsigned short* obf = ybf + TOKP * 256;
    unsigned short* xbf  = (unsigned short*)take((size_t)8192 * 192 * 2);
    // weight buffers: rows padded to multiples of 64 (B-tile staging reads them)
    unsigned short* We1  = (unsigned short*)take((size_t)512 * 192 * 2);
    unsigned short* We2  = (unsigned short*)take((size_t)256 * 480 * 2);
    unsigned short* Wqkv = (unsigned short*)take((size_t)NB_ * 768 * 256 * 2);
    unsigned short* WoT  = (unsigned short*)take((size_t)NB_ * 256 * 256 * 2);
    unsigned short* W1T  = (unsigned short*)take((size_t)NB_ * 512 * 256 * 2);
    unsigned short* W2T  = (unsigned short*)take((size_t)NB_ * 256 * 480 * 2);
    // qkv packed region; embed LN1 bf16 out [8192][480] aliases qp+kp (dead before attn_init)
    _Float16* qp = (_Float16*)take(QN * 3 * 2);
    _Float16* kp = qp + QN;
    _Float16* vp = kp + QN;
    unsigned short* t480bf = (unsigned short*)qp;

    const int BS = 256;
    auto blocks = [](size_t n) { return (int)((n + 255) / 256); };

    // prep
    mask_kernel<<<blocks(TOK), BS, 0, stream>>>(x, mask);
    pack_bias<<<NB_, BS, 0, stream>>>(bq, bk, bv, b720);
    cvt_x<<<8192, 64, 0, stream>>>(x, xbf);
    pretrans<<<dim3(480, 1), 64, 0, stream>>>(e_W1, We1, PD_, 480, 192, 0, 0);
    pretrans<<<dim3(240, 1), 64, 0, stream>>>(e_W2, We2, 480, 240, 480, 0, 0);
    pretrans<<<dim3(240, NB_), 64, 0, stream>>>(Wq, Wqkv,           240, 240, 256, 240*240, 768*256);
    pretrans<<<dim3(240, NB_), 64, 0, stream>>>(Wk, Wqkv + 240*256, 240, 240, 256, 240*240, 768*256);
    pretrans<<<dim3(240, NB_), 64, 0, stream>>>(Wv, Wqkv + 480*256, 240, 240, 256, 240*240, 768*256);
    pretrans<<<dim3(240, NB_), 64, 0, stream>>>(Wo, WoT,            240, 240, 256, 240*240, 256*256);
    pretrans<<<dim3(480, NB_), 64, 0, stream>>>(W1, W1T,            240, 480, 256, 240*480, 512*256);
    pretrans<<<dim3(240, NB_), 64, 0, stream>>>(W2, W2T,            480, 240, 480, 480*240, 256*480);

    // embed
    gemm_mfma<<<dim3(64, 8), BS, 0, stream>>>(xbf, We1, e_b1, tmp1, nullptr,
                                              nullptr, nullptr, nullptr,
                                              8192, 480, 192, 480, 0);
    ln480<<<2048, BS, 0, stream>>>(tmp1, t480bf, e_g1, e_bn1);
    gemm_mfma<<<dim3(64, 4), BS, 0, stream>>>(t480bf, We2, e_b2, y32, nullptr,
                                              nullptr, nullptr, nullptr,
                                              8192, 240, 480, 240, 0);
    embed_finish<<<(int)TOK, BS, 0, stream>>>(y32, e_g2, e_bn2, pos, cls, h);
    attn_init<<<blocks((size_t)B_ * H_ * LP_), BS, 0, stream>>>(mask, qp, kp, vp);

    for (int i = 0; i < NB_; i++) {
        ln240<<<(int)(TOK / 4), BS, 0, stream>>>(h, ybf, ln1_g + i * D_, ln1_b + i * D_);
        gemm_mfma<<<dim3(65, 12), BS, 0, stream>>>(ybf, Wqkv + (size_t)i * 768 * 256,
                                                   b720 + i * 720, nullptr, nullptr,
                                                   qp, kp, vp,
                                                   (int)TOK, 720, 256, 0, 4);
        attn_kernel<<<dim3(H_, B_), 320, 0, stream>>>(qp, kp, vp, obf);
        gemm_mfma<<<dim3(65, 4), BS, 0, stream>>>(obf, WoT + (size_t)i * 256 * 256,
                                                  bo + i * D_, h, nullptr,
                                                  nullptr, nullptr, nullptr,
                                                  (int)TOK, 240, 256, 240, 2);
        ln240<<<(int)(TOK / 4), BS, 0, stream>>>(h, ybf, ln2_g + i * D_, ln2_b + i * D_);
        gemm_mfma<<<dim3(65, 8), BS, 0, stream>>>(ybf, W1T + (size_t)i * 512 * 256,
                                                  b1 + i * HID_, nullptr, tbf,
                                                  nullptr, nullptr, nullptr,
                                                  (int)TOK, 480, 256, 480, 1 | 8);
        gemm_mfma<<<dim3(65, 4), BS, 0, stream>>>(tbf, W2T + (size_t)i * 256 * 480,
                                                  b2 + i * D_, h, nullptr,
                                                  nullptr, nullptr, nullptr,
                                                  (int)TOK, 240, 480, 240, 2);
    }

    pool_kernel<<<B_, BS, 0, stream>>>(h, mask, pl);
    logits_kernel<<<blocks((size_t)B_ * NC_), BS, 0, stream>>>(pl, logit_W, logit_b, out);
}

// Round 6
// 953.135 us; speedup vs baseline: 8.9167x; 1.2361x over previous
//
#include <hip/hip_runtime.h>
#include <math.h>

#define B_  32
#define L_  256
#define PD_ 164
#define D_  240
#define H_  16
#define NB_ 6
#define NC_ 250
#define DK_ 15
#define HID_ 480
#define LP_ 257
#define KP_ 288            // keys padded to 9*32
#define SCALE_ 0.2581988897471611f   // 1/sqrt(15)
#define LOG2E_ 1.4426950408889634f

typedef __attribute__((ext_vector_type(8))) short bf16x8;
typedef __attribute__((ext_vector_type(8))) _Float16 f16x8;
typedef __attribute__((ext_vector_type(4))) float f32x4;

static __device__ inline unsigned short f2bf(float x) {
    unsigned u = __builtin_bit_cast(unsigned, x);
    u += 0x7FFFu + ((u >> 16) & 1u);     // RNE (finite values only)
    return (unsigned short)(u >> 16);
}
static __device__ inline unsigned short f2h(float x) {
    _Float16 h = (_Float16)x;
    return __builtin_bit_cast(unsigned short, h);
}

// async global->LDS, 16B per lane; lds dest must be wave-uniform base (+lane*16)
static __device__ inline void gl2lds16(const void* g, void* l) {
    __builtin_amdgcn_global_load_lds(
        (const __attribute__((address_space(1))) unsigned int*)g,
        (__attribute__((address_space(3))) unsigned int*)l, 16, 0, 0);
}

// ---------------- mask ----------------
__global__ void mask_kernel(const float* __restrict__ x, float* __restrict__ mask) {
    int idx = blockIdx.x * blockDim.x + threadIdx.x;
    if (idx >= B_ * LP_) return;
    int b = idx / LP_, l = idx % LP_;
    if (l == 0) { mask[idx] = 0.f; return; }
    const float* xr = x + ((size_t)b * L_ + (l - 1)) * PD_;
    float mx = -1e30f;
    for (int j = 0; j < PD_; j++) mx = fmaxf(mx, xr[j]);
    mask[idx] = (mx == 0.f) ? 1.f : 0.f;
}

// --------- x fp32 [8192][164] -> bf16 [8192][192] (zero pad) -----------------
__global__ void cvt_x(const float* __restrict__ x, unsigned short* __restrict__ xbf) {
    int row = blockIdx.x;
    const float* src = x + (size_t)row * PD_;
    unsigned short* dst = xbf + (size_t)row * 192;
    for (int k = threadIdx.x; k < 192; k += 64)
        dst[k] = f2bf(k < PD_ ? src[k] : 0.f);
}

// --------- weight pretranspose: fp32 [batch][K][N] -> bf16 [batch][N][Kpad] --
__global__ void pretrans(const float* __restrict__ W, unsigned short* __restrict__ out,
                         int K, int N, int Kpad, long sstride, long dstride) {
    int n = blockIdx.x, bb = blockIdx.y;
    const float* src = W + (size_t)bb * sstride;
    unsigned short* dst = out + (size_t)bb * dstride + (size_t)n * Kpad;
    for (int k = threadIdx.x; k < Kpad; k += 64)
        dst[k] = f2bf((k < K && n < N) ? src[(size_t)k * N + n] : 0.f);
}

// --------- init c==15 lanes of packed q/k/v --------------------------------
// q[15]=log2e (bf16), k[15]=-10000 if masked else 0 (bf16), v[15]=1.0 (f16,
// ones-column: PV output col 15 = softmax denominator)
__global__ void attn_init(const float* __restrict__ mask, unsigned short* __restrict__ qp,
                          unsigned short* __restrict__ kp, unsigned short* __restrict__ vp) {
    int idx = blockIdx.x * blockDim.x + threadIdx.x;   // (b*H+h)*LP + l
    if (idx >= B_ * H_ * LP_) return;
    int l = idx % LP_;
    int b = idx / (H_ * LP_);
    qp[(size_t)idx * 16 + 15] = f2bf(LOG2E_);
    kp[(size_t)idx * 16 + 15] = (mask[b * LP_ + l] != 0.f) ? f2bf(-10000.f) : 0;
    vp[(size_t)idx * 16 + 15] = f2h(1.f);
}

// --------- pack bq|bk|bv per layer into one 720-vector -----------------------
__global__ void pack_bias(const float* __restrict__ bq, const float* __restrict__ bk,
                          const float* __restrict__ bv, float* __restrict__ b720) {
    int i = blockIdx.x;
    for (int n = threadIdx.x; n < 720; n += 256) {
        float v = (n < 240) ? bq[i * 240 + n]
                : (n < 480) ? bk[i * 240 + n - 240]
                            : bv[i * 240 + n - 480];
        b720[i * 720 + n] = v;
    }
}

// ---------------- MFMA GEMM: C = A[M,Kpad]bf16 @ Bt[N,Kpad]bf16 --------------
// tile 128x64, 4 waves (2x2), K-step 32. Staging via global_load_lds.
// flags: 1 relu, 2 accumulate fp32 C, 4 QKV-packed epilogue, 8 bf16 out
__global__ __launch_bounds__(256)
void gemm_mfma(const unsigned short* __restrict__ A,
               const unsigned short* __restrict__ Bt,
               const float* __restrict__ bias,
               float* __restrict__ C, unsigned short* __restrict__ Cbf,
               unsigned short* __restrict__ qp, unsigned short* __restrict__ kp,
               unsigned short* __restrict__ vp,
               int M, int N, int Kpad, int Cstride, int flags)
{
    __shared__ __align__(16) unsigned short As[128 * 32];   // 8 KB
    __shared__ __align__(16) unsigned short Bs[64 * 32];    // 4 KB
    const int tid = threadIdx.x;
    const int bm = blockIdx.x * 128;
    const int bn = blockIdx.y * 64;
    const int wave = tid >> 6, lane = tid & 63;
    const int wm = (wave & 1) * 64, wn = (wave >> 1) * 32;
    const int lq = lane >> 4, lr = lane & 15;

    f32x4 acc[4][2];
    #pragma unroll
    for (int i = 0; i < 4; i++)
        #pragma unroll
        for (int j = 0; j < 2; j++) acc[i][j] = (f32x4){0.f, 0.f, 0.f, 0.f};

    const int srow = lane >> 2;            // 0..15
    const int schk = (lane & 3) << 3;      // 0,8,16,24
    const unsigned short* ga0 = A + (size_t)(bm + wave * 32 + srow) * Kpad + schk;
    const unsigned short* ga1 = A + (size_t)(bm + wave * 32 + 16 + srow) * Kpad + schk;
    const unsigned short* gb  = Bt + (size_t)(bn + wave * 16 + srow) * Kpad + schk;
    char* la0 = (char*)As + wave * 2048;
    char* la1 = (char*)As + wave * 2048 + 1024;
    char* lb  = (char*)Bs + wave * 1024;

    const int nkt = Kpad >> 5;
    for (int kt = 0; kt < nkt; kt++) {
        gl2lds16(ga0, la0);
        gl2lds16(ga1, la1);
        gl2lds16(gb, lb);
        ga0 += 32; ga1 += 32; gb += 32;
        __syncthreads();
        bf16x8 af[4], bfr[2];
        #pragma unroll
        for (int i = 0; i < 4; i++)
            af[i] = *(const bf16x8*)&As[(wm + i * 16 + lr) * 32 + lq * 8];
        #pragma unroll
        for (int j = 0; j < 2; j++)
            bfr[j] = *(const bf16x8*)&Bs[(wn + j * 16 + lr) * 32 + lq * 8];
        #pragma unroll
        for (int i = 0; i < 4; i++)
            #pragma unroll
            for (int j = 0; j < 2; j++)
                acc[i][j] = __builtin_amdgcn_mfma_f32_16x16x32_bf16(af[i], bfr[j], acc[i][j], 0, 0, 0);
        __syncthreads();
    }

    if (flags & 4) {                       // QKV packed epilogue (N=720)
        #pragma unroll
        for (int j = 0; j < 2; j++) {
            int n = bn + wn + j * 16 + lr;
            if (n >= N) continue;
            int which = n / 240;
            int rem = n - which * 240;
            int hh = rem / 15;
            int c = rem - hh * 15;
            unsigned short* dst = (which == 0) ? qp : (which == 1) ? kp : vp;
            float bias_n = bias[n];
            float mult = (which == 0) ? (SCALE_ * LOG2E_) : 1.f;
            #pragma unroll
            for (int i = 0; i < 4; i++)
                #pragma unroll
                for (int r = 0; r < 4; r++) {
                    int m = bm + wm + i * 16 + lq * 4 + r;
                    if (m >= M) continue;
                    float s = (acc[i][j][r] + bias_n) * mult;
                    int b = m / LP_, l = m - b * LP_;
                    unsigned short bits = (which == 2) ? f2h(s) : f2bf(s);
                    dst[(((size_t)b * H_ + hh) * LP_ + l) * 16 + c] = bits;
                }
        }
    } else if (flags & 8) {                // bf16 output
        #pragma unroll
        for (int i = 0; i < 4; i++)
            #pragma unroll
            for (int j = 0; j < 2; j++) {
                int n = bn + wn + j * 16 + lr;
                if (n >= N) continue;
                float bias_n = bias ? bias[n] : 0.f;
                #pragma unroll
                for (int r = 0; r < 4; r++) {
                    int m = bm + wm + i * 16 + lq * 4 + r;
                    if (m >= M) continue;
                    float s = acc[i][j][r] + bias_n;
                    if (flags & 1) s = fmaxf(s, 0.f);
                    Cbf[(size_t)m * Cstride + n] = f2bf(s);
                }
            }
    } else {                               // fp32 output (optionally accumulate)
        #pragma unroll
        for (int i = 0; i < 4; i++)
            #pragma unroll
            for (int j = 0; j < 2; j++) {
                int n = bn + wn + j * 16 + lr;
                if (n >= N) continue;
                float bias_n = bias ? bias[n] : 0.f;
                #pragma unroll
                for (int r = 0; r < 4; r++) {
                    int m = bm + wm + i * 16 + lq * 4 + r;
                    if (m >= M) continue;
                    float s = acc[i][j][r] + bias_n;
                    if (flags & 1) s = fmaxf(s, 0.f);
                    size_t off = (size_t)m * Cstride + n;
                    if (flags & 2) C[off] += s; else C[off] = s;
                }
            }
    }
}

// ------------- LN240: wave-per-row, fp32 in -> bf16 out [rows][256] ----------
__global__ __launch_bounds__(256)
void ln240(const float* __restrict__ in, unsigned short* __restrict__ out,
           const float* __restrict__ g, const float* __restrict__ bb) {
    const int row = blockIdx.x * 4 + (threadIdx.x >> 6);
    const int lane = threadIdx.x & 63;
    const float* x = in + (size_t)row * 240;
    float4 v = {0.f, 0.f, 0.f, 0.f};
    if (lane < 60) v = *(const float4*)(x + lane * 4);
    float s = (v.x + v.y) + (v.z + v.w);
    #pragma unroll
    for (int off = 32; off; off >>= 1) s += __shfl_xor(s, off);
    const float mean = s * (1.f / 240.f);
    float4 d;
    d.x = v.x - mean; d.y = v.y - mean; d.z = v.z - mean; d.w = v.w - mean;
    float vs = (lane < 60) ? (d.x * d.x + d.y * d.y) + (d.z * d.z + d.w * d.w) : 0.f;
    #pragma unroll
    for (int off = 32; off; off >>= 1) vs += __shfl_xor(vs, off);
    const float rs = rsqrtf(vs * (1.f / 240.f) + 1e-5f);
    ushort4 o4 = {0, 0, 0, 0};
    if (lane < 60) {
        float4 g4 = *(const float4*)(g + lane * 4);
        float4 b4 = *(const float4*)(bb + lane * 4);
        o4.x = f2bf(d.x * rs * g4.x + b4.x);
        o4.y = f2bf(d.y * rs * g4.y + b4.y);
        o4.z = f2bf(d.z * rs * g4.z + b4.z);
        o4.w = f2bf(d.w * rs * g4.w + b4.w);
    }
    *(ushort4*)(out + (size_t)row * 256 + lane * 4) = o4;   // lanes 60..63: pad zeros
}

// ------------- LN480+relu: wave-per-row, fp32 in -> bf16 out [rows][480] -----
__global__ __launch_bounds__(256)
void ln480(const float* __restrict__ in, unsigned short* __restrict__ out,
           const float* __restrict__ g, const float* __restrict__ bb) {
    const int row = blockIdx.x * 4 + (threadIdx.x >> 6);
    const int lane = threadIdx.x & 63;
    const float* x = in + (size_t)row * 480;
    float4 va = {0.f,0.f,0.f,0.f}, vb = {0.f,0.f,0.f,0.f};
    if (lane < 60) {
        va = *(const float4*)(x + lane * 8);
        vb = *(const float4*)(x + lane * 8 + 4);
    }
    float s = ((va.x + va.y) + (va.z + va.w)) + ((vb.x + vb.y) + (vb.z + vb.w));
    #pragma unroll
    for (int off = 32; off; off >>= 1) s += __shfl_xor(s, off);
    const float mean = s * (1.f / 480.f);
    float4 da, db;
    da.x = va.x - mean; da.y = va.y - mean; da.z = va.z - mean; da.w = va.w - mean;
    db.x = vb.x - mean; db.y = vb.y - mean; db.z = vb.z - mean; db.w = vb.w - mean;
    float vs = (lane < 60) ? ((da.x*da.x + da.y*da.y) + (da.z*da.z + da.w*da.w)) +
                             ((db.x*db.x + db.y*db.y) + (db.z*db.z + db.w*db.w)) : 0.f;
    #pragma unroll
    for (int off = 32; off; off >>= 1) vs += __shfl_xor(vs, off);
    const float rs = rsqrtf(vs * (1.f / 480.f) + 1e-5f);
    if (lane < 60) {
        float4 ga = *(const float4*)(g + lane * 8);
        float4 gb = *(const float4*)(g + lane * 8 + 4);
        float4 ba = *(const float4*)(bb + lane * 8);
        float4 b2 = *(const float4*)(bb + lane * 8 + 4);
        ushort4 oa, ob;
        oa.x = f2bf(fmaxf(da.x * rs * ga.x + ba.x, 0.f));
        oa.y = f2bf(fmaxf(da.y * rs * ga.y + ba.y, 0.f));
        oa.z = f2bf(fmaxf(da.z * rs * ga.z + ba.z, 0.f));
        oa.w = f2bf(fmaxf(da.w * rs * ga.w + ba.w, 0.f));
        ob.x = f2bf(fmaxf(db.x * rs * gb.x + b2.x, 0.f));
        ob.y = f2bf(fmaxf(db.y * rs * gb.y + b2.y, 0.f));
        ob.z = f2bf(fmaxf(db.z * rs * gb.z + b2.z, 0.f));
        ob.w = f2bf(fmaxf(db.w * rs * gb.w + b2.w, 0.f));
        *(ushort4*)(out + (size_t)row * 480 + lane * 8) = oa;
        *(ushort4*)(out + (size_t)row * 480 + lane * 8 + 4) = ob;
    }
}

// -------- embed finish: LN(g2)+relu+pos for tokens, cls row for l==0 ---------
__global__ void embed_finish(const float* __restrict__ tmp,
                             const float* __restrict__ g, const float* __restrict__ bb,
                             const float* __restrict__ pos, const float* __restrict__ cls,
                             float* __restrict__ h) {
    int row = blockIdx.x;
    int b = row / LP_, l = row % LP_;
    int t = threadIdx.x;
    float* out = h + (size_t)row * D_;
    if (l == 0) {
        if (t < D_) out[t] = cls[t];
        return;
    }
    const float* x = tmp + ((size_t)b * L_ + (l - 1)) * D_;
    float v0 = (t < D_) ? x[t] : 0.f;
    __shared__ float red[256];
    red[t] = v0;
    __syncthreads();
    for (int off = 128; off > 0; off >>= 1) {
        if (t < off) red[t] += red[t + off];
        __syncthreads();
    }
    float mean = red[0] / D_;
    __syncthreads();
    float d0 = (t < D_) ? v0 - mean : 0.f;
    red[t] = d0 * d0;
    __syncthreads();
    for (int off = 128; off > 0; off >>= 1) {
        if (t < off) red[t] += red[t + off];
        __syncthreads();
    }
    float rs = rsqrtf(red[0] / D_ + 1e-5f);
    if (t < D_) {
        float r = d0 * rs * g[t] + bb[t];
        out[t] = fmaxf(r, 0.f) + pos[(size_t)(l - 1) * D_ + t];
    }
}

// ---------------- MFMA flash attention: block per (b,h), 4 waves -------------
// S = Q K^T via 16x16x32_bf16 (K-dim 16 real + 16 zero); p = exp2(s) -> P (f16)
// in per-wave LDS; O = P V via 16x16x32_f16 with V^T staged; V col 15 is the
// ones-column so O[:,15] = softmax denominator. Keys padded to 288 with
// k[15] = -10000 sentinel (p -> 0).
__global__ __launch_bounds__(256)
void attn_mfma(const unsigned short* __restrict__ qp, const unsigned short* __restrict__ kp,
               const unsigned short* __restrict__ vp, unsigned short* __restrict__ obf)
{
    __shared__ __align__(16) unsigned short Kl[KP_ * 24];    // 13.5 KB (cols 0..15 used)
    __shared__ __align__(16) unsigned short Vt[16 * 296];    // 9.25 KB  V^T f16
    __shared__ __align__(16) unsigned short Pl[4][16 * 296]; // 37 KB    P f16 per wave
    const int hh = blockIdx.x, b = blockIdx.y;
    const int tid = threadIdx.x;
    const int wave = tid >> 6, lane = tid & 63;
    const int lq = lane >> 4, lr = lane & 15;
    const size_t base = ((size_t)b * H_ + hh) * LP_ * 16;

    // ---- stage K (bf16) and V^T (f16) ----
    for (int key = tid; key < KP_; key += 256) {
        uint4 z = {0u, 0u, 0u, 0u};
        uint4 k0 = z, k1 = z, v0 = z, v1 = z;
        if (key < LP_) {
            k0 = *(const uint4*)(kp + base + (size_t)key * 16);
            k1 = *(const uint4*)(kp + base + (size_t)key * 16 + 8);
            v0 = *(const uint4*)(vp + base + (size_t)key * 16);
            v1 = *(const uint4*)(vp + base + (size_t)key * 16 + 8);
        } else {
            k1.w = 0xC61C0000u;            // elem15 = bf16(-10000) sentinel
        }
        *(uint4*)&Kl[key * 24] = k0;
        *(uint4*)&Kl[key * 24 + 8] = k1;
        unsigned short vs[8];
        *(uint4*)vs = v0;
        #pragma unroll
        for (int d = 0; d < 8; d++) Vt[d * 296 + key] = vs[d];
        *(uint4*)vs = v1;
        #pragma unroll
        for (int d = 0; d < 8; d++) Vt[(d + 8) * 296 + key] = vs[d];
    }
    __syncthreads();

    unsigned short* Pw = &Pl[wave][0];
    for (int qt = wave; qt < 17; qt += 4) {
        const int qrow = qt * 16 + lr;
        bf16x8 aq = {0, 0, 0, 0, 0, 0, 0, 0};
        if (lq < 2)
            aq = *(const bf16x8*)(qp + base + (size_t)qrow * 16 + lq * 8);
        // ---- S pass: 18 key tiles ----
        for (int kt = 0; kt < 18; kt++) {
            bf16x8 bk = {0, 0, 0, 0, 0, 0, 0, 0};
            if (lq < 2)
                bk = *(const bf16x8*)&Kl[(kt * 16 + lr) * 24 + lq * 8];
            f32x4 sacc = {0.f, 0.f, 0.f, 0.f};
            sacc = __builtin_amdgcn_mfma_f32_16x16x32_bf16(aq, bk, sacc, 0, 0, 0);
            // D: col(key-in-tile)=lr, row(query-in-tile)=lq*4+r
            #pragma unroll
            for (int r = 0; r < 4; r++)
                Pw[(lq * 4 + r) * 296 + kt * 16 + lr] = f2h(exp2f(sacc[r]));
        }
        asm volatile("s_waitcnt lgkmcnt(0)" ::: "memory");
        // ---- PV pass: 9 k-steps of 32 keys ----
        f32x4 o = {0.f, 0.f, 0.f, 0.f};
        #pragma unroll
        for (int ks = 0; ks < 9; ks++) {
            f16x8 ap = *(const f16x8*)&Pw[lr * 296 + ks * 32 + lq * 8];
            f16x8 bv = *(const f16x8*)&Vt[lr * 296 + ks * 32 + lq * 8];
            o = __builtin_amdgcn_mfma_f32_16x16x32_f16(ap, bv, o, 0, 0, 0);
        }
        asm volatile("s_waitcnt lgkmcnt(0)" ::: "memory");
        // D: col(d)=lr, row(query-in-tile)=lq*4+r ; col 15 = denominator
        #pragma unroll
        for (int r = 0; r < 4; r++) {
            float denom = __shfl(o[r], lane | 15);
            int q = qt * 16 + lq * 4 + r;
            if (q < LP_ && lr < 15)
                obf[((size_t)b * LP_ + q) * 256 + hh * DK_ + lr] = f2bf(o[r] / denom);
        }
    }
}

// ---------------- masked mean pool (2-stage) ---------------------------------
__global__ void pool_partial(const float* __restrict__ h, const float* __restrict__ mask,
                             float* __restrict__ partial) {
    int b = blockIdx.x, slice = blockIdx.y;
    int d = threadIdx.x;
    if (d >= D_) return;
    float s = 0.f;
    int l0 = slice * 29;
    for (int i = 0; i < 29; i++) {
        int l = l0 + i;
        if (l < LP_ && mask[b * LP_ + l] == 0.f)
            s += h[((size_t)b * LP_ + l) * D_ + d];
    }
    partial[((size_t)b * 9 + slice) * D_ + d] = s;
}

__global__ void pool_final(const float* __restrict__ partial, const float* __restrict__ mask,
                           float* __restrict__ pool) {
    int b = blockIdx.x;
    int t = threadIdx.x;
    __shared__ float red[256];
    float c = 0.f;
    for (int l = t; l < LP_; l += 256) c += (mask[b * LP_ + l] == 0.f) ? 1.f : 0.f;
    red[t] = c;
    __syncthreads();
    for (int off = 128; off > 0; off >>= 1) {
        if (t < off) red[t] += red[t + off];
        __syncthreads();
    }
    float inv = 1.f / red[0];
    if (t < D_) {
        float s = 0.f;
        #pragma unroll
        for (int sl = 0; sl < 9; sl++) s += partial[((size_t)b * 9 + sl) * D_ + t];
        pool[b * D_ + t] = s * inv;
    }
}

// ---------------- logits -----------------------------------------------------
__global__ void logits_kernel(const float* __restrict__ pool, const float* __restrict__ W,
                              const float* __restrict__ bias, float* __restrict__ out) {
    int idx = blockIdx.x * blockDim.x + threadIdx.x;
    if (idx >= B_ * NC_) return;
    int b = idx / NC_, n = idx - b * NC_;
    float s = bias[n];
    const float* p = pool + b * D_;
    for (int kk = 0; kk < D_; kk++) s += p[kk] * W[(size_t)kk * NC_ + n];
    out[idx] = s;
}

extern "C" void kernel_launch(void* const* d_in, const int* in_sizes, int n_in,
                              void* d_out, int out_size, void* d_ws, size_t ws_size,
                              hipStream_t stream) {
    const float* x        = (const float*)d_in[0];
    const float* pos      = (const float*)d_in[1];
    const float* cls      = (const float*)d_in[2];
    const float* e_W1     = (const float*)d_in[3];
    const float* e_b1     = (const float*)d_in[4];
    const float* e_g1     = (const float*)d_in[5];
    const float* e_bn1    = (const float*)d_in[6];
    const float* e_W2     = (const float*)d_in[7];
    const float* e_b2     = (const float*)d_in[8];
    const float* e_g2     = (const float*)d_in[9];
    const float* e_bn2    = (const float*)d_in[10];
    const float* ln1_g    = (const float*)d_in[11];
    const float* ln1_b    = (const float*)d_in[12];
    const float* Wq       = (const float*)d_in[13];
    const float* bq       = (const float*)d_in[14];
    const float* Wk       = (const float*)d_in[15];
    const float* bk       = (const float*)d_in[16];
    const float* Wv       = (const float*)d_in[17];
    const float* bv       = (const float*)d_in[18];
    const float* Wo       = (const float*)d_in[19];
    const float* bo       = (const float*)d_in[20];
    const float* ln2_g    = (const float*)d_in[21];
    const float* ln2_b    = (const float*)d_in[22];
    const float* W1       = (const float*)d_in[23];
    const float* b1       = (const float*)d_in[24];
    const float* W2       = (const float*)d_in[25];
    const float* b2       = (const float*)d_in[26];
    const float* logit_W  = (const float*)d_in[27];
    const float* logit_b  = (const float*)d_in[28];
    float* out = (float*)d_out;

    const size_t TOK  = (size_t)B_ * LP_;            // 8224
    const size_t TOKP = 8320;                        // padded to 65*128
    const size_t HN   = TOK * D_;
    const size_t QN   = (size_t)B_ * H_ * LP_ * 16;  // 2,105,344

    // ---- workspace layout (bytes, 16B aligned) ----
    char* wsb = (char*)d_ws;
    size_t cur = 0;
    auto take = [&](size_t bytes) { void* p = wsb + cur; cur += (bytes + 15) & ~15ULL; return p; };
    float* mask = (float*)take(8224 * 4);
    float* h    = (float*)take(HN * 4);
    float* b720 = (float*)take(NB_ * 720 * 4);
    float* pl   = (float*)take(B_ * D_ * 4);
    float* part = (float*)take((size_t)B_ * 9 * D_ * 4);
    // region A: embed gemm1 fp32 out [8192][480]  <->  FFN hidden bf16 [8320][480]
    void* regionA = take((size_t)8192 * 480 * 4);
    float* tmp1 = (float*)regionA;
    unsigned short* tbf = (unsigned short*)regionA;
    // region B: embed gemm2 fp32 out [8192][240] <-> ybf[8320][256]+obf[8320][256]
    void* regionB = take(TOKP * 256 * 2 * 2);
    float* y32 = (float*)regionB;
    unsigned short* ybf = (unsigned short*)regionB;
    unsigned short* obf = ybf + TOKP * 256;
    unsigned short* xbf  = (unsigned short*)take((size_t)8192 * 192 * 2);
    // weight buffers: rows padded to multiples of 64 (B-tile staging reads them)
    unsigned short* We1  = (unsigned short*)take((size_t)512 * 192 * 2);
    unsigned short* We2  = (unsigned short*)take((size_t)256 * 480 * 2);
    unsigned short* Wqkv = (unsigned short*)take((size_t)NB_ * 768 * 256 * 2);
    unsigned short* WoT  = (unsigned short*)take((size_t)NB_ * 256 * 256 * 2);
    unsigned short* W1T  = (unsigned short*)take((size_t)NB_ * 512 * 256 * 2);
    unsigned short* W2T  = (unsigned short*)take((size_t)NB_ * 256 * 480 * 2);
    // qkv packed region; embed LN1 bf16 out [8192][480] aliases qp+kp (dead before attn_init)
    unsigned short* qp = (unsigned short*)take(QN * 3 * 2 + 16 * 16 * 2);
    unsigned short* kp = qp + QN;
    unsigned short* vp = kp + QN;
    unsigned short* t480bf = qp;

    const int BS = 256;
    auto blocks = [](size_t n) { return (int)((n + 255) / 256); };

    // prep
    mask_kernel<<<blocks(TOK), BS, 0, stream>>>(x, mask);
    pack_bias<<<NB_, BS, 0, stream>>>(bq, bk, bv, b720);
    cvt_x<<<8192, 64, 0, stream>>>(x, xbf);
    pretrans<<<dim3(480, 1), 64, 0, stream>>>(e_W1, We1, PD_, 480, 192, 0, 0);
    pretrans<<<dim3(240, 1), 64, 0, stream>>>(e_W2, We2, 480, 240, 480, 0, 0);
    pretrans<<<dim3(240, NB_), 64, 0, stream>>>(Wq, Wqkv,           240, 240, 256, 240*240, 768*256);
    pretrans<<<dim3(240, NB_), 64, 0, stream>>>(Wk, Wqkv + 240*256, 240, 240, 256, 240*240, 768*256);
    pretrans<<<dim3(240, NB_), 64, 0, stream>>>(Wv, Wqkv + 480*256, 240, 240, 256, 240*240, 768*256);
    pretrans<<<dim3(240, NB_), 64, 0, stream>>>(Wo, WoT,            240, 240, 256, 240*240, 256*256);
    pretrans<<<dim3(480, NB_), 64, 0, stream>>>(W1, W1T,            240, 480, 256, 240*480, 512*256);
    pretrans<<<dim3(240, NB_), 64, 0, stream>>>(W2, W2T,            480, 240, 480, 480*240, 256*480);

    // embed
    gemm_mfma<<<dim3(64, 8), BS, 0, stream>>>(xbf, We1, e_b1, tmp1, nullptr,
                                              nullptr, nullptr, nullptr,
                                              8192, 480, 192, 480, 0);
    ln480<<<2048, BS, 0, stream>>>(tmp1, t480bf, e_g1, e_bn1);
    gemm_mfma<<<dim3(64, 4), BS, 0, stream>>>(t480bf, We2, e_b2, y32, nullptr,
                                              nullptr, nullptr, nullptr,
                                              8192, 240, 480, 240, 0);
    embed_finish<<<(int)TOK, BS, 0, stream>>>(y32, e_g2, e_bn2, pos, cls, h);
    hipMemsetAsync(obf, 0, TOKP * 256 * 2, stream);   // zero pad cols 240..255 (y32 dead now)
    attn_init<<<blocks((size_t)B_ * H_ * LP_), BS, 0, stream>>>(mask, qp, kp, vp);

    for (int i = 0; i < NB_; i++) {
        ln240<<<(int)(TOK / 4), BS, 0, stream>>>(h, ybf, ln1_g + i * D_, ln1_b + i * D_);
        gemm_mfma<<<dim3(65, 12), BS, 0, stream>>>(ybf, Wqkv + (size_t)i * 768 * 256,
                                                   b720 + i * 720, nullptr, nullptr,
                                                   qp, kp, vp,
                                                   (int)TOK, 720, 256, 0, 4);
        attn_mfma<<<dim3(H_, B_), BS, 0, stream>>>(qp, kp, vp, obf);
        gemm_mfma<<<dim3(65, 4), BS, 0, stream>>>(obf, WoT + (size_t)i * 256 * 256,
                                                  bo + i * D_, h, nullptr,
                                                  nullptr, nullptr, nullptr,
                                                  (int)TOK, 240, 256, 240, 2);
        ln240<<<(int)(TOK / 4), BS, 0, stream>>>(h, ybf, ln2_g + i * D_, ln2_b + i * D_);
        gemm_mfma<<<dim3(65, 8), BS, 0, stream>>>(ybf, W1T + (size_t)i * 512 * 256,
                                                  b1 + i * HID_, nullptr, tbf,
                                                  nullptr, nullptr, nullptr,
                                                  (int)TOK, 480, 256, 480, 1 | 8);
        gemm_mfma<<<dim3(65, 4), BS, 0, stream>>>(tbf, W2T + (size_t)i * 256 * 480,
                                                  b2 + i * D_, h, nullptr,
                                                  nullptr, nullptr, nullptr,
                                                  (int)TOK, 240, 480, 240, 2);
    }

    pool_partial<<<dim3(B_, 9), BS, 0, stream>>>(h, mask, part);
    pool_final<<<B_, BS, 0, stream>>>(part, mask, pl);
    logits_kernel<<<blocks((size_t)B_ * NC_), BS, 0, stream>>>(pl, logit_W, logit_b, out);
}